// Round 7
// baseline (368.801 us; speedup 1.0000x reference)
//
#include <hip/hip_runtime.h>
#include <cstdint>
#include <cstddef>

// ---------------- bf16 pack/unpack helpers (RNE) ----------------

__device__ inline unsigned pack_bf16x2(float a, float b) {
    unsigned ua = __float_as_uint(a);
    unsigned ub = __float_as_uint(b);
    ua += 0x7fffu + ((ua >> 16) & 1u);
    ub += 0x7fffu + ((ub >> 16) & 1u);
    return (ua >> 16) | (ub & 0xffff0000u);
}
__device__ inline float bf16lo(unsigned u) { return __uint_as_float(u << 16); }
__device__ inline float bf16hi(unsigned u) { return __uint_as_float(u & 0xffff0000u); }

typedef int iv4 __attribute__((ext_vector_type(4)));

#define NPART 8      // dst-partitions (XCD locality)
#define SRCB  16     // src bins -> adjacency comes out src-bin-sorted
#define NBUK  (NPART * SRCB)
#define KB    32     // blocks per dst-partition in count/fill passes
#define NPP_MAX 12500

// ---------------- CSR build: counting sort keyed (dst-part, src-bin) ----------

__global__ void k_zeroN(int* __restrict__ p, int n) {
    int i = blockIdx.x * blockDim.x + threadIdx.x;
    if (i < n) p[i] = 0;
}

// A1: global bucket sizes. LDS-reduced, NBUK global atomics/block.
__global__ __launch_bounds__(256) void k_bcount(const int* __restrict__ src,
                                                const int* __restrict__ dst,
                                                int* __restrict__ bucketCount,
                                                int E, int npp, int spp) {
    __shared__ int c[NBUK];
    for (int i = threadIdx.x; i < NBUK; i += 256) c[i] = 0;
    __syncthreads();
    int t = blockIdx.x * blockDim.x + threadIdx.x;
    int stride = gridDim.x * blockDim.x;
    int E4 = E >> 2;
    const iv4* d4 = (const iv4*)dst;
    const iv4* s4 = (const iv4*)src;
    for (int i = t; i < E4; i += stride) {
        iv4 d = d4[i];
        iv4 s = s4[i];
        atomicAdd(&c[((unsigned)d.x / (unsigned)npp) * SRCB + (unsigned)s.x / (unsigned)spp], 1);
        atomicAdd(&c[((unsigned)d.y / (unsigned)npp) * SRCB + (unsigned)s.y / (unsigned)spp], 1);
        atomicAdd(&c[((unsigned)d.z / (unsigned)npp) * SRCB + (unsigned)s.z / (unsigned)spp], 1);
        atomicAdd(&c[((unsigned)d.w / (unsigned)npp) * SRCB + (unsigned)s.w / (unsigned)spp], 1);
    }
    for (int e = E4 * 4 + t; e < E; e += stride)
        atomicAdd(&c[((unsigned)dst[e] / (unsigned)npp) * SRCB +
                     (unsigned)src[e] / (unsigned)spp], 1);
    __syncthreads();
    for (int i = threadIdx.x; i < NBUK; i += 256) atomicAdd(&bucketCount[i], c[i]);
}

// A2: serial scan of NBUK buckets (dst-major => dst-part ranges contiguous,
// internally ascending src-bin). Also per-dst-part base/count.
__global__ void k_bscan(const int* __restrict__ bucketCount,
                        int* __restrict__ bucketBase,
                        int* __restrict__ bucketCursor,
                        int* __restrict__ dpBase, int* __restrict__ dpCount) {
    if (threadIdx.x == 0) {
        int run = 0;
        for (int b = 0; b < NBUK; ++b) {
            bucketBase[b] = run;
            bucketCursor[b] = run;
            run += bucketCount[b];
        }
        for (int p = 0; p < NPART; ++p) {
            dpBase[p] = bucketBase[p * SRCB];
            int s = 0;
            for (int q = 0; q < SRCB; ++q) s += bucketCount[p * SRCB + q];
            dpCount[p] = s;
        }
    }
}

// A3: scatter edges into bucket segments as (dst,src) pairs.
__global__ __launch_bounds__(256) void k_bucket(const int* __restrict__ src,
                                                const int* __restrict__ dst,
                                                int* __restrict__ bucketCursor,
                                                int2* __restrict__ pairs,
                                                int E, int npp, int spp) {
    __shared__ int cnt[NBUK], run[NBUK], gbase[NBUK];
    int tid = threadIdx.x;
    int base_e = blockIdx.x * 4096 + tid * 16;
    int nv = min(16, E - base_e);
    if (nv < 0) nv = 0;
    int dv[16], sv[16];
    if (nv == 16) {
        for (int q = 0; q < 4; ++q) {
            iv4 d = *(const iv4*)(dst + base_e + q * 4);
            iv4 s = *(const iv4*)(src + base_e + q * 4);
            dv[q * 4 + 0] = d.x; dv[q * 4 + 1] = d.y; dv[q * 4 + 2] = d.z; dv[q * 4 + 3] = d.w;
            sv[q * 4 + 0] = s.x; sv[q * 4 + 1] = s.y; sv[q * 4 + 2] = s.z; sv[q * 4 + 3] = s.w;
        }
    } else {
        for (int k = 0; k < nv; ++k) { dv[k] = dst[base_e + k]; sv[k] = src[base_e + k]; }
    }
    for (int i = tid; i < NBUK; i += 256) { cnt[i] = 0; run[i] = 0; }
    __syncthreads();
    for (int k = 0; k < nv; ++k)
        atomicAdd(&cnt[((unsigned)dv[k] / (unsigned)npp) * SRCB +
                       (unsigned)sv[k] / (unsigned)spp], 1);
    __syncthreads();
    for (int i = tid; i < NBUK; i += 256)
        if (cnt[i]) gbase[i] = atomicAdd(&bucketCursor[i], cnt[i]);
    __syncthreads();
    for (int k = 0; k < nv; ++k) {
        int b = ((unsigned)dv[k] / (unsigned)npp) * SRCB + (unsigned)sv[k] / (unsigned)spp;
        int r = atomicAdd(&run[b], 1);
        int2 pr; pr.x = dv[k]; pr.y = sv[k];
        pairs[gbase[b] + r] = pr;
    }
}

// B: per-(partition,block) LDS histogram over the block's chunk of the
// dst-part's (src-bin-ordered) range; flush with plain stores.
__global__ __launch_bounds__(256) void k_count_part(const int2* __restrict__ pairs,
                                                    const int* __restrict__ dpBase,
                                                    const int* __restrict__ dpCount,
                                                    int* __restrict__ cntarr, int npp) {
    __shared__ int h[NPP_MAX];
    int p = blockIdx.x & (NPART - 1);
    int b = blockIdx.x >> 3;
    int lo = p * npp;
    for (int i = threadIdx.x; i < npp; i += 256) h[i] = 0;
    __syncthreads();
    int segBase = dpBase[p], sz = dpCount[p];
    int chunk = (sz + KB - 1) / KB;
    int s0 = segBase + b * chunk;
    int s1 = min(segBase + sz, s0 + chunk);
    for (int i = s0 + threadIdx.x; i < s1; i += 256)
        atomicAdd(&h[pairs[i].x - lo], 1);
    __syncthreads();
    size_t out = (size_t)(p * KB + b) * npp;
    for (int i = threadIdx.x; i < npp; i += 256) cntarr[out + i] = h[i];
}

// C1: indeg[d] = sum over KB blocks of partial counts.
__global__ void k_indeg(const int* __restrict__ cntarr, int* __restrict__ indeg,
                        int n, int npp) {
    int d = blockIdx.x * blockDim.x + threadIdx.x;
    if (d >= n) return;
    int p = (unsigned)d / (unsigned)npp;
    int dl = d - p * npp;
    size_t base = (size_t)p * KB * npp + dl;
    int s = 0;
    for (int b = 0; b < KB; ++b) s += cntarr[base + (size_t)b * npp];
    indeg[d] = s;
}

__global__ void k_scan_local(const int* __restrict__ in, int* __restrict__ out,
                             int* __restrict__ partials, int n) {
    __shared__ int s[256];
    int t = threadIdx.x;
    int base = blockIdx.x * 1024 + t * 4;
    int v0 = (base + 0) < n ? in[base + 0] : 0;
    int v1 = (base + 1) < n ? in[base + 1] : 0;
    int v2 = (base + 2) < n ? in[base + 2] : 0;
    int v3 = (base + 3) < n ? in[base + 3] : 0;
    int sum = v0 + v1 + v2 + v3;
    s[t] = sum;
    __syncthreads();
    for (int off = 1; off < 256; off <<= 1) {
        int x = (t >= off) ? s[t - off] : 0;
        __syncthreads();
        s[t] += x;
        __syncthreads();
    }
    int excl = s[t] - sum;
    if ((base + 0) < n) out[base + 0] = excl;
    if ((base + 1) < n) out[base + 1] = excl + v0;
    if ((base + 2) < n) out[base + 2] = excl + v0 + v1;
    if ((base + 3) < n) out[base + 3] = excl + v0 + v1 + v2;
    if (t == 255) partials[blockIdx.x] = s[255];
}

__global__ void k_scan_partials(int* __restrict__ partials, int np) {
    __shared__ int s[256];
    int t = threadIdx.x;
    int v = (t < np) ? partials[t] : 0;
    s[t] = v;
    __syncthreads();
    for (int off = 1; off < 256; off <<= 1) {
        int x = (t >= off) ? s[t - off] : 0;
        __syncthreads();
        s[t] += x;
        __syncthreads();
    }
    if (t < np) partials[t] = s[t] - v;
}

__global__ void k_finalize(int* __restrict__ row_ptr, const int* __restrict__ partials,
                           const int* __restrict__ indeg, float* __restrict__ dinv,
                           int n, int E) {
    int i = blockIdx.x * blockDim.x + threadIdx.x;
    if (i < n) {
        int rp = row_ptr[i] + partials[i >> 10];
        row_ptr[i] = rp;
        dinv[i] = rsqrtf((float)indeg[i] + 1.0f);  // +1 = self loop
        if (i == 0) row_ptr[n] = E;
    }
}

// C2: partial counts -> per-(block,dst) base offsets (block order = src-bin order,
// so adjacency lists come out ascending in src-bin).
__global__ void k_bases(int* __restrict__ cntarr, const int* __restrict__ row_ptr,
                        int n, int npp) {
    int d = blockIdx.x * blockDim.x + threadIdx.x;
    if (d >= n) return;
    int p = (unsigned)d / (unsigned)npp;
    int dl = d - p * npp;
    size_t base = (size_t)p * KB * npp + dl;
    int run = row_ptr[d];
    for (int b = 0; b < KB; ++b) {
        size_t idx = base + (size_t)b * npp;
        int c = cntarr[idx];
        cntarr[idx] = run;
        run += c;
    }
}

// D: atomic-free fill via private LDS cursors.
__global__ __launch_bounds__(256) void k_fill2(const int2* __restrict__ pairs,
                                               const int* __restrict__ dpBase,
                                               const int* __restrict__ dpCount,
                                               const int* __restrict__ cntarr,
                                               int* __restrict__ col, int npp) {
    __shared__ int cur[NPP_MAX];
    int p = blockIdx.x & (NPART - 1);
    int b = blockIdx.x >> 3;
    int lo = p * npp;
    size_t slice = (size_t)(p * KB + b) * npp;
    for (int i = threadIdx.x; i < npp; i += 256) cur[i] = cntarr[slice + i];
    __syncthreads();
    int segBase = dpBase[p], sz = dpCount[p];
    int chunk = (sz + KB - 1) / KB;
    int s0 = segBase + b * chunk;
    int s1 = min(segBase + sz, s0 + chunk);
    for (int i = s0 + threadIdx.x; i < s1; i += 256) {
        int2 e = pairs[i];
        int pos = atomicAdd(&cur[e.x - lo], 1);
        col[pos] = e.y;
    }
}

// ---------------- GEMMs — epilogue: row *= dinv[row], store bf16 ----------------

// Hb[N x 64 uints] = bf16x2( dinv[row] * (X @ W1) ); X fp32.
__global__ __launch_bounds__(256) void k_gemm128(const float* __restrict__ X,
                                                 const float* __restrict__ W,
                                                 const float* __restrict__ dinv,
                                                 unsigned* __restrict__ Hb) {
    __shared__ float Wl[32 * 128];
    __shared__ float Xs[32 * 32];
    int t = threadIdx.x;
    size_t row0 = (size_t)blockIdx.x * 32;
    int r0 = (t >> 5) * 4;
    int c0 = (t & 31) * 4;
    int lr = t >> 3, lk = (t & 7) * 4;
    float acc[4][4] = {};
    for (int kc = 0; kc < 128; kc += 32) {
        __syncthreads();
        for (int idx = t; idx < 1024; idx += 256)
            ((float4*)Wl)[idx] = ((const float4*)W)[kc * 32 + idx];
        *(float4*)(Xs + lr * 32 + lk) =
            *(const float4*)(X + (row0 + lr) * 128 + kc + lk);
        __syncthreads();
        for (int kk = 0; kk < 32; kk += 4) {
            float a[4][4], wv[4][4];
            for (int r = 0; r < 4; r++) {
                float4 av = *(const float4*)(Xs + (r0 + r) * 32 + kk);
                a[r][0] = av.x; a[r][1] = av.y; a[r][2] = av.z; a[r][3] = av.w;
            }
            for (int j = 0; j < 4; j++) {
                float4 wq = *(const float4*)(Wl + (kk + j) * 128 + c0);
                wv[j][0] = wq.x; wv[j][1] = wq.y; wv[j][2] = wq.z; wv[j][3] = wq.w;
            }
            for (int r = 0; r < 4; r++)
                for (int j = 0; j < 4; j++)
                    for (int c = 0; c < 4; c++)
                        acc[r][c] += a[r][j] * wv[j][c];
        }
    }
    for (int r = 0; r < 4; r++) {
        float di = dinv[row0 + r0 + r];
        uint2 o = {pack_bf16x2(di * acc[r][0], di * acc[r][1]),
                   pack_bf16x2(di * acc[r][2], di * acc[r][3])};
        *(uint2*)(Hb + (row0 + r0 + r) * 64 + (c0 >> 1)) = o;
    }
}

// Hb[N x 32 uints] = bf16x2( dinv[row] * (A1 @ W2) ); A1 is packed bf16 (64 uints/row).
__global__ __launch_bounds__(256) void k_gemm64(const unsigned* __restrict__ Xb,
                                                const float* __restrict__ W,
                                                const float* __restrict__ dinv,
                                                unsigned* __restrict__ Hb) {
    __shared__ float Wl[32 * 64];
    __shared__ float Xs[32 * 32];
    int t = threadIdx.x;
    size_t row0 = (size_t)blockIdx.x * 32;
    int r0 = (t >> 4) * 2;
    int c0 = (t & 15) * 4;
    int lr = t >> 3, lk = (t & 7) * 4;
    float acc[2][4] = {};
    for (int kc = 0; kc < 128; kc += 32) {
        __syncthreads();
        ((float4*)Wl)[t]       = ((const float4*)W)[kc * 16 + t];
        ((float4*)Wl)[t + 256] = ((const float4*)W)[kc * 16 + t + 256];
        {
            uint2 u = *(const uint2*)(Xb + (row0 + lr) * 64 + ((kc + lk) >> 1));
            float4 xv = {bf16lo(u.x), bf16hi(u.x), bf16lo(u.y), bf16hi(u.y)};
            *(float4*)(Xs + lr * 32 + lk) = xv;
        }
        __syncthreads();
        for (int kk = 0; kk < 32; kk += 4) {
            float a[2][4], wv[4][4];
            for (int r = 0; r < 2; r++) {
                float4 av = *(const float4*)(Xs + (r0 + r) * 32 + kk);
                a[r][0] = av.x; a[r][1] = av.y; a[r][2] = av.z; a[r][3] = av.w;
            }
            for (int j = 0; j < 4; j++) {
                float4 wq = *(const float4*)(Wl + (kk + j) * 64 + c0);
                wv[j][0] = wq.x; wv[j][1] = wq.y; wv[j][2] = wq.z; wv[j][3] = wq.w;
            }
            for (int r = 0; r < 2; r++)
                for (int j = 0; j < 4; j++)
                    for (int c = 0; c < 4; c++)
                        acc[r][c] += a[r][j] * wv[j][c];
        }
    }
    for (int r = 0; r < 2; r++) {
        float di = dinv[row0 + r0 + r];
        uint2 o = {pack_bf16x2(di * acc[r][0], di * acc[r][1]),
                   pack_bf16x2(di * acc[r][2], di * acc[r][3])};
        *(uint2*)(Hb + (row0 + r0 + r) * 32 + (c0 >> 1)) = o;
    }
}

// ---------------- Pull-mode aggregation (bf16 payload, fp32 accumulate) ----------

// out (a1) stored as packed bf16 (64 uints/row).
__global__ __launch_bounds__(256) void k_agg_relu(const unsigned* __restrict__ hs,
                                                  const float* __restrict__ dinv,
                                                  const int* __restrict__ row_ptr,
                                                  const int* __restrict__ col,
                                                  const float* __restrict__ bias,
                                                  unsigned* __restrict__ out, int n) {
    int node = blockIdx.x * 4 + (threadIdx.x >> 6);
    if (node >= n) return;
    int lane = threadIdx.x & 63;
    unsigned su = hs[(size_t)node * 64 + lane];
    float ax = bf16lo(su), ay = bf16hi(su);
    int p0 = row_ptr[node], p1 = row_ptr[node + 1];
    for (int base = p0; base < p1; base += 64) {
        int nb = min(64, p1 - base);
        int myc = col[base + min(lane, nb - 1)];
        int k = 0;
        for (; k + 4 <= nb; k += 4) {
            int j0 = __shfl(myc, k);
            int j1 = __shfl(myc, k + 1);
            int j2 = __shfl(myc, k + 2);
            int j3 = __shfl(myc, k + 3);
            unsigned v0 = hs[(size_t)j0 * 64 + lane];
            unsigned v1 = hs[(size_t)j1 * 64 + lane];
            unsigned v2 = hs[(size_t)j2 * 64 + lane];
            unsigned v3 = hs[(size_t)j3 * 64 + lane];
            ax += (bf16lo(v0) + bf16lo(v1)) + (bf16lo(v2) + bf16lo(v3));
            ay += (bf16hi(v0) + bf16hi(v1)) + (bf16hi(v2) + bf16hi(v3));
        }
        for (; k < nb; ++k) {
            int j = __shfl(myc, k);
            unsigned v = hs[(size_t)j * 64 + lane];
            ax += bf16lo(v);
            ay += bf16hi(v);
        }
    }
    float di = dinv[node];
    ax = fmaf(di, ax, bias[2 * lane]);
    ay = fmaf(di, ay, bias[2 * lane + 1]);
    ax = ax > 0.f ? ax : 0.f;
    ay = ay > 0.f ? ay : 0.f;
    out[(size_t)node * 64 + lane] = pack_bf16x2(ax, ay);
}

__global__ __launch_bounds__(256) void k_agg_lsm(const unsigned short* __restrict__ hs,
                                                 const float* __restrict__ dinv,
                                                 const int* __restrict__ row_ptr,
                                                 const int* __restrict__ col,
                                                 const float* __restrict__ bias,
                                                 float* __restrict__ out, int n) {
    int node = blockIdx.x * 4 + (threadIdx.x >> 6);
    if (node >= n) return;
    int lane = threadIdx.x & 63;
    float acc = __uint_as_float(((unsigned)hs[(size_t)node * 64 + lane]) << 16);
    int p0 = row_ptr[node], p1 = row_ptr[node + 1];
    for (int base = p0; base < p1; base += 64) {
        int nb = min(64, p1 - base);
        int myc = col[base + min(lane, nb - 1)];
        int k = 0;
        for (; k + 4 <= nb; k += 4) {
            int j0 = __shfl(myc, k);
            int j1 = __shfl(myc, k + 1);
            int j2 = __shfl(myc, k + 2);
            int j3 = __shfl(myc, k + 3);
            float v0 = __uint_as_float(((unsigned)hs[(size_t)j0 * 64 + lane]) << 16);
            float v1 = __uint_as_float(((unsigned)hs[(size_t)j1 * 64 + lane]) << 16);
            float v2 = __uint_as_float(((unsigned)hs[(size_t)j2 * 64 + lane]) << 16);
            float v3 = __uint_as_float(((unsigned)hs[(size_t)j3 * 64 + lane]) << 16);
            acc += (v0 + v1) + (v2 + v3);
        }
        for (; k < nb; ++k) {
            int j = __shfl(myc, k);
            acc += __uint_as_float(((unsigned)hs[(size_t)j * 64 + lane]) << 16);
        }
    }
    float v = fmaf(dinv[node], acc, bias[lane]);
    float m = v;
    for (int off = 32; off; off >>= 1) m = fmaxf(m, __shfl_xor(m, off));
    float e = __expf(v - m);
    float s = e;
    for (int off = 32; off; off >>= 1) s += __shfl_xor(s, off);
    out[(size_t)node * 64 + lane] = v - m - __logf(s);
}

// ---------------- launcher ----------------

extern "C" void kernel_launch(void* const* d_in, const int* in_sizes, int n_in,
                              void* d_out, int out_size, void* d_ws, size_t ws_size,
                              hipStream_t stream) {
    const float* x  = (const float*)d_in[0];
    const int*   ei = (const int*)d_in[1];
    const float* W1 = (const float*)d_in[2];
    const float* b1 = (const float*)d_in[3];
    const float* W2 = (const float*)d_in[4];
    const float* b2 = (const float*)d_in[5];
    float* out = (float*)d_out;

    const int N = in_sizes[0] / 128;   // 100000
    const int E = in_sizes[1] / 2;     // 1600000
    const int* src = ei;
    const int* dst = ei + E;
    const int npp = (N + NPART - 1) / NPART;  // 12500
    const int spp = (N + SRCB - 1) / SRCB;    // 6250

    // workspace carve (256B aligned)
    char* w = (char*)d_ws;
    size_t off = 0;
    auto alloc = [&](size_t bytes) -> void* {
        void* p = w + off;
        off += (bytes + 255) & ~(size_t)255;
        return p;
    };
    int*      indeg    = (int*)alloc((size_t)N * 4);
    int*      row_ptr  = (int*)alloc((size_t)(N + 1) * 4);
    int*      colarr   = (int*)alloc((size_t)E * 4);
    int*      partials = (int*)alloc(256 * 4);
    int*      bcnt     = (int*)alloc(NBUK * 4);
    int*      bcur     = (int*)alloc(NBUK * 4);
    int*      bbase    = (int*)alloc(NBUK * 4);
    int*      dpBase   = (int*)alloc(NPART * 4);
    int*      dpCount  = (int*)alloc(NPART * 4);
    float*    dinv     = (float*)alloc((size_t)N * 4);
    unsigned* h1b      = (unsigned*)alloc((size_t)N * 64 * 4);  // bf16 X@W1 scaled
    unsigned* a1b      = (unsigned*)alloc((size_t)N * 64 * 4);  // bf16 relu out
    unsigned* h2b      = (unsigned*)alloc((size_t)N * 32 * 4);  // bf16 a1@W2 scaled
    // CSR-build temporaries overlay a1b (dead until agg_relu): pairs + counts
    int2* pairs  = (int2*)a1b;                                  // E*8 = 12.8 MB
    int*  cntarr = (int*)((char*)a1b + (size_t)E * 8);          // 8*32*npp*4 = 12.8 MB
    (void)ws_size; (void)n_in; (void)out_size;

    int nscan = (N + 1023) / 1024;
    int nA3 = (E + 4095) / 4096;

    k_zeroN<<<1, NBUK, 0, stream>>>(bcnt, NBUK);
    k_bcount<<<256, 256, 0, stream>>>(src, dst, bcnt, E, npp, spp);
    k_bscan<<<1, 64, 0, stream>>>(bcnt, bbase, bcur, dpBase, dpCount);
    k_bucket<<<nA3, 256, 0, stream>>>(src, dst, bcur, pairs, E, npp, spp);
    k_count_part<<<NPART * KB, 256, 0, stream>>>(pairs, dpBase, dpCount, cntarr, npp);
    k_indeg<<<(N + 255) / 256, 256, 0, stream>>>(cntarr, indeg, N, npp);
    k_scan_local<<<nscan, 256, 0, stream>>>(indeg, row_ptr, partials, N);
    k_scan_partials<<<1, 256, 0, stream>>>(partials, nscan);
    k_finalize<<<(N + 255) / 256, 256, 0, stream>>>(row_ptr, partials, indeg, dinv, N, E);
    k_bases<<<(N + 255) / 256, 256, 0, stream>>>(cntarr, row_ptr, N, npp);
    k_fill2<<<NPART * KB, 256, 0, stream>>>(pairs, dpBase, dpCount, cntarr, colarr, npp);

    k_gemm128<<<N / 32, 256, 0, stream>>>(x, W1, dinv, h1b);
    k_agg_relu<<<(N + 3) / 4, 256, 0, stream>>>(h1b, dinv, row_ptr, colarr, b1, a1b, N);
    k_gemm64<<<N / 32, 256, 0, stream>>>(a1b, W2, dinv, h2b);
    k_agg_lsm<<<(N + 3) / 4, 256, 0, stream>>>((const unsigned short*)h2b, dinv,
                                               row_ptr, colarr, b2, out, N);
}

// Round 8
// 339.387 us; speedup vs baseline: 1.0867x; 1.0867x over previous
//
#include <hip/hip_runtime.h>
#include <hip/hip_fp16.h>
#include <cstdint>
#include <cstddef>
#include <cstring>

// ---------------- bf16 pack/unpack helpers (RNE) ----------------

__device__ inline unsigned pack_bf16x2(float a, float b) {
    unsigned ua = __float_as_uint(a);
    unsigned ub = __float_as_uint(b);
    ua += 0x7fffu + ((ua >> 16) & 1u);
    ub += 0x7fffu + ((ub >> 16) & 1u);
    return (ua >> 16) | (ub & 0xffff0000u);
}
__device__ inline float bf16lo(unsigned u) { return __uint_as_float(u << 16); }
__device__ inline float bf16hi(unsigned u) { return __uint_as_float(u & 0xffff0000u); }

// ---------------- fp8 (OCP e4m3fn) pack/unpack ----------------
// HW path: gfx950 v_cvt_pk_* instructions. Fallback: exact bit path via f16
// (fp8 bits << 7 into f16 field gives value*2^-8; scale back by 256).

typedef float fv2 __attribute__((ext_vector_type(2)));

__device__ inline float2 fp8x2_to_f32(unsigned u2) {  // u2: 2 fp8 in low 16 bits
#if __has_builtin(__builtin_amdgcn_cvt_pk_f32_fp8)
    fv2 r = __builtin_amdgcn_cvt_pk_f32_fp8((int)u2, false);
    return make_float2(r.x, r.y);
#else
    unsigned w = (u2 & 0xFFu) | ((u2 & 0xFF00u) << 8);
    unsigned hb = ((w & 0x00800080u) << 8) | ((w & 0x007f007fu) << 7);
    __half2 h2;
    memcpy(&h2, &hb, 4);
    float2 f = __half22float2(h2);
    f.x *= 256.0f;
    f.y *= 256.0f;
    return f;
#endif
}

__device__ inline unsigned f32_to_fp8_byte(float v) {  // fallback helper
    unsigned short hb = __half_as_ushort(__float2half(v * 0.00390625f));  // v/256
    unsigned t = hb & 0x7fffu;
    t += 0x3fu + ((t >> 7) & 1u);  // RNE on the 7 dropped mantissa bits
    return ((hb >> 8) & 0x80u) | (t >> 7);
}

__device__ inline unsigned pack4_fp8(float a0, float a1, float a2, float a3) {
#if __has_builtin(__builtin_amdgcn_cvt_pk_fp8_f32)
    int u = __builtin_amdgcn_cvt_pk_fp8_f32(a0, a1, 0, false);
    u = __builtin_amdgcn_cvt_pk_fp8_f32(a2, a3, u, true);
    return (unsigned)u;
#else
    return f32_to_fp8_byte(a0) | (f32_to_fp8_byte(a1) << 8) |
           (f32_to_fp8_byte(a2) << 16) | (f32_to_fp8_byte(a3) << 24);
#endif
}

typedef int iv4 __attribute__((ext_vector_type(4)));

#define NPART 8      // dst-partitions == XCDs (blockIdx%8 locality heuristic)
#define KB    32     // blocks per partition in count/fill passes
#define NPP_MAX 12500

// ---------------- CSR build: atomic-free counting-sort pipeline (R6 form) -------

__global__ void k_zero16(int* __restrict__ p) {
    if (threadIdx.x < 16) p[threadIdx.x] = 0;
}

__global__ __launch_bounds__(256) void k_bcount(const int* __restrict__ dst,
                                                int* __restrict__ bucketCount,
                                                int E, int npp) {
    __shared__ int c8[NPART];
    if (threadIdx.x < NPART) c8[threadIdx.x] = 0;
    __syncthreads();
    int t = blockIdx.x * blockDim.x + threadIdx.x;
    int stride = gridDim.x * blockDim.x;
    int E4 = E >> 2;
    const iv4* d4 = (const iv4*)dst;
    for (int i = t; i < E4; i += stride) {
        iv4 d = d4[i];
        atomicAdd(&c8[(unsigned)d.x / (unsigned)npp], 1);
        atomicAdd(&c8[(unsigned)d.y / (unsigned)npp], 1);
        atomicAdd(&c8[(unsigned)d.z / (unsigned)npp], 1);
        atomicAdd(&c8[(unsigned)d.w / (unsigned)npp], 1);
    }
    for (int e = E4 * 4 + t; e < E; e += stride)
        atomicAdd(&c8[(unsigned)dst[e] / (unsigned)npp], 1);
    __syncthreads();
    if (threadIdx.x < NPART) atomicAdd(&bucketCount[threadIdx.x], c8[threadIdx.x]);
}

__global__ void k_bscan(const int* __restrict__ bucketCount,
                        int* __restrict__ bucketBase,
                        int* __restrict__ bucketCursor) {
    if (threadIdx.x == 0) {
        int run = 0;
        for (int p = 0; p < NPART; ++p) {
            bucketBase[p] = run;
            bucketCursor[p] = run;
            run += bucketCount[p];
        }
    }
}

__global__ __launch_bounds__(256) void k_bucket(const int* __restrict__ src,
                                                const int* __restrict__ dst,
                                                int* __restrict__ bucketCursor,
                                                int2* __restrict__ pairs,
                                                int E, int npp) {
    __shared__ int cnt8[NPART], run8[NPART], gbase8[NPART];
    int tid = threadIdx.x;
    int base_e = blockIdx.x * 4096 + tid * 16;
    int nv = min(16, E - base_e);
    if (nv < 0) nv = 0;
    int dv[16], sv[16];
    if (nv == 16) {
        for (int q = 0; q < 4; ++q) {
            iv4 d = *(const iv4*)(dst + base_e + q * 4);
            iv4 s = *(const iv4*)(src + base_e + q * 4);
            dv[q * 4 + 0] = d.x; dv[q * 4 + 1] = d.y; dv[q * 4 + 2] = d.z; dv[q * 4 + 3] = d.w;
            sv[q * 4 + 0] = s.x; sv[q * 4 + 1] = s.y; sv[q * 4 + 2] = s.z; sv[q * 4 + 3] = s.w;
        }
    } else {
        for (int k = 0; k < nv; ++k) { dv[k] = dst[base_e + k]; sv[k] = src[base_e + k]; }
    }
    if (tid < NPART) { cnt8[tid] = 0; run8[tid] = 0; }
    __syncthreads();
    for (int k = 0; k < nv; ++k)
        atomicAdd(&cnt8[(unsigned)dv[k] / (unsigned)npp], 1);
    __syncthreads();
    if (tid < NPART) gbase8[tid] = atomicAdd(&bucketCursor[tid], cnt8[tid]);
    __syncthreads();
    for (int k = 0; k < nv; ++k) {
        int p = (unsigned)dv[k] / (unsigned)npp;
        int r = atomicAdd(&run8[p], 1);
        int2 pr; pr.x = dv[k]; pr.y = sv[k];
        pairs[gbase8[p] + r] = pr;
    }
}

__global__ __launch_bounds__(256) void k_count_part(const int2* __restrict__ pairs,
                                                    const int* __restrict__ bucketBase,
                                                    const int* __restrict__ bucketCount,
                                                    int* __restrict__ cntarr, int npp) {
    __shared__ int h[NPP_MAX];
    int p = blockIdx.x & (NPART - 1);
    int b = blockIdx.x >> 3;
    int lo = p * npp;
    for (int i = threadIdx.x; i < npp; i += 256) h[i] = 0;
    __syncthreads();
    int segBase = bucketBase[p], sz = bucketCount[p];
    int chunk = (sz + KB - 1) / KB;
    int s0 = segBase + b * chunk;
    int s1 = min(segBase + sz, s0 + chunk);
    for (int i = s0 + threadIdx.x; i < s1; i += 256)
        atomicAdd(&h[pairs[i].x - lo], 1);
    __syncthreads();
    size_t out = (size_t)(p * KB + b) * npp;
    for (int i = threadIdx.x; i < npp; i += 256) cntarr[out + i] = h[i];
}

__global__ void k_indeg(const int* __restrict__ cntarr, int* __restrict__ indeg,
                        int n, int npp) {
    int d = blockIdx.x * blockDim.x + threadIdx.x;
    if (d >= n) return;
    int p = (unsigned)d / (unsigned)npp;
    int dl = d - p * npp;
    size_t base = (size_t)p * KB * npp + dl;
    int s = 0;
    for (int b = 0; b < KB; ++b) s += cntarr[base + (size_t)b * npp];
    indeg[d] = s;
}

__global__ void k_scan_local(const int* __restrict__ in, int* __restrict__ out,
                             int* __restrict__ partials, int n) {
    __shared__ int s[256];
    int t = threadIdx.x;
    int base = blockIdx.x * 1024 + t * 4;
    int v0 = (base + 0) < n ? in[base + 0] : 0;
    int v1 = (base + 1) < n ? in[base + 1] : 0;
    int v2 = (base + 2) < n ? in[base + 2] : 0;
    int v3 = (base + 3) < n ? in[base + 3] : 0;
    int sum = v0 + v1 + v2 + v3;
    s[t] = sum;
    __syncthreads();
    for (int off = 1; off < 256; off <<= 1) {
        int x = (t >= off) ? s[t - off] : 0;
        __syncthreads();
        s[t] += x;
        __syncthreads();
    }
    int excl = s[t] - sum;
    if ((base + 0) < n) out[base + 0] = excl;
    if ((base + 1) < n) out[base + 1] = excl + v0;
    if ((base + 2) < n) out[base + 2] = excl + v0 + v1;
    if ((base + 3) < n) out[base + 3] = excl + v0 + v1 + v2;
    if (t == 255) partials[blockIdx.x] = s[255];
}

__global__ void k_scan_partials(int* __restrict__ partials, int np) {
    __shared__ int s[256];
    int t = threadIdx.x;
    int v = (t < np) ? partials[t] : 0;
    s[t] = v;
    __syncthreads();
    for (int off = 1; off < 256; off <<= 1) {
        int x = (t >= off) ? s[t - off] : 0;
        __syncthreads();
        s[t] += x;
        __syncthreads();
    }
    if (t < np) partials[t] = s[t] - v;
}

__global__ void k_finalize(int* __restrict__ row_ptr, const int* __restrict__ partials,
                           const int* __restrict__ indeg, float* __restrict__ dinv,
                           int n, int E) {
    int i = blockIdx.x * blockDim.x + threadIdx.x;
    if (i < n) {
        int rp = row_ptr[i] + partials[i >> 10];
        row_ptr[i] = rp;
        dinv[i] = rsqrtf((float)indeg[i] + 1.0f);  // +1 = self loop
        if (i == 0) row_ptr[n] = E;
    }
}

__global__ void k_bases(int* __restrict__ cntarr, const int* __restrict__ row_ptr,
                        int n, int npp) {
    int d = blockIdx.x * blockDim.x + threadIdx.x;
    if (d >= n) return;
    int p = (unsigned)d / (unsigned)npp;
    int dl = d - p * npp;
    size_t base = (size_t)p * KB * npp + dl;
    int run = row_ptr[d];
    for (int b = 0; b < KB; ++b) {
        size_t idx = base + (size_t)b * npp;
        int c = cntarr[idx];
        cntarr[idx] = run;
        run += c;
    }
}

__global__ __launch_bounds__(256) void k_fill2(const int2* __restrict__ pairs,
                                               const int* __restrict__ bucketBase,
                                               const int* __restrict__ bucketCount,
                                               const int* __restrict__ cntarr,
                                               int* __restrict__ col, int npp) {
    __shared__ int cur[NPP_MAX];
    int p = blockIdx.x & (NPART - 1);
    int b = blockIdx.x >> 3;
    int lo = p * npp;
    size_t slice = (size_t)(p * KB + b) * npp;
    for (int i = threadIdx.x; i < npp; i += 256) cur[i] = cntarr[slice + i];
    __syncthreads();
    int segBase = bucketBase[p], sz = bucketCount[p];
    int chunk = (sz + KB - 1) / KB;
    int s0 = segBase + b * chunk;
    int s1 = min(segBase + sz, s0 + chunk);
    for (int i = s0 + threadIdx.x; i < s1; i += 256) {
        int2 e = pairs[i];
        int pos = atomicAdd(&cur[e.x - lo], 1);
        col[pos] = e.y;
    }
}

// ---------------- GEMMs — epilogue: row *= dinv[row], store fp8 / bf16 ----------

// Hf8[N x 32 uints] = fp8x4( dinv[row] * (X @ W1) ); X fp32.
__global__ __launch_bounds__(256) void k_gemm128(const float* __restrict__ X,
                                                 const float* __restrict__ W,
                                                 const float* __restrict__ dinv,
                                                 unsigned* __restrict__ Hf8) {
    __shared__ float Wl[32 * 128];
    __shared__ float Xs[32 * 32];
    int t = threadIdx.x;
    size_t row0 = (size_t)blockIdx.x * 32;
    int r0 = (t >> 5) * 4;
    int c0 = (t & 31) * 4;
    int lr = t >> 3, lk = (t & 7) * 4;
    float acc[4][4] = {};
    for (int kc = 0; kc < 128; kc += 32) {
        __syncthreads();
        for (int idx = t; idx < 1024; idx += 256)
            ((float4*)Wl)[idx] = ((const float4*)W)[kc * 32 + idx];
        *(float4*)(Xs + lr * 32 + lk) =
            *(const float4*)(X + (row0 + lr) * 128 + kc + lk);
        __syncthreads();
        for (int kk = 0; kk < 32; kk += 4) {
            float a[4][4], wv[4][4];
            for (int r = 0; r < 4; r++) {
                float4 av = *(const float4*)(Xs + (r0 + r) * 32 + kk);
                a[r][0] = av.x; a[r][1] = av.y; a[r][2] = av.z; a[r][3] = av.w;
            }
            for (int j = 0; j < 4; j++) {
                float4 wq = *(const float4*)(Wl + (kk + j) * 128 + c0);
                wv[j][0] = wq.x; wv[j][1] = wq.y; wv[j][2] = wq.z; wv[j][3] = wq.w;
            }
            for (int r = 0; r < 4; r++)
                for (int j = 0; j < 4; j++)
                    for (int c = 0; c < 4; c++)
                        acc[r][c] += a[r][j] * wv[j][c];
        }
    }
    for (int r = 0; r < 4; r++) {
        float di = dinv[row0 + r0 + r];
        Hf8[(row0 + r0 + r) * 32 + (c0 >> 2)] =
            pack4_fp8(di * acc[r][0], di * acc[r][1], di * acc[r][2], di * acc[r][3]);
    }
}

// Hb[N x 32 uints] = bf16x2( dinv[row] * (A1 @ W2) ); A1 is packed bf16 (64 uints/row).
__global__ __launch_bounds__(256) void k_gemm64(const unsigned* __restrict__ Xb,
                                                const float* __restrict__ W,
                                                const float* __restrict__ dinv,
                                                unsigned* __restrict__ Hb) {
    __shared__ float Wl[32 * 64];
    __shared__ float Xs[32 * 32];
    int t = threadIdx.x;
    size_t row0 = (size_t)blockIdx.x * 32;
    int r0 = (t >> 4) * 2;
    int c0 = (t & 15) * 4;
    int lr = t >> 3, lk = (t & 7) * 4;
    float acc[2][4] = {};
    for (int kc = 0; kc < 128; kc += 32) {
        __syncthreads();
        ((float4*)Wl)[t]       = ((const float4*)W)[kc * 16 + t];
        ((float4*)Wl)[t + 256] = ((const float4*)W)[kc * 16 + t + 256];
        {
            uint2 u = *(const uint2*)(Xb + (row0 + lr) * 64 + ((kc + lk) >> 1));
            float4 xv = {bf16lo(u.x), bf16hi(u.x), bf16lo(u.y), bf16hi(u.y)};
            *(float4*)(Xs + lr * 32 + lk) = xv;
        }
        __syncthreads();
        for (int kk = 0; kk < 32; kk += 4) {
            float a[2][4], wv[4][4];
            for (int r = 0; r < 2; r++) {
                float4 av = *(const float4*)(Xs + (r0 + r) * 32 + kk);
                a[r][0] = av.x; a[r][1] = av.y; a[r][2] = av.z; a[r][3] = av.w;
            }
            for (int j = 0; j < 4; j++) {
                float4 wq = *(const float4*)(Wl + (kk + j) * 64 + c0);
                wv[j][0] = wq.x; wv[j][1] = wq.y; wv[j][2] = wq.z; wv[j][3] = wq.w;
            }
            for (int r = 0; r < 2; r++)
                for (int j = 0; j < 4; j++)
                    for (int c = 0; c < 4; c++)
                        acc[r][c] += a[r][j] * wv[j][c];
        }
    }
    for (int r = 0; r < 2; r++) {
        float di = dinv[row0 + r0 + r];
        uint2 o = {pack_bf16x2(di * acc[r][0], di * acc[r][1]),
                   pack_bf16x2(di * acc[r][2], di * acc[r][3])};
        *(uint2*)(Hb + (row0 + r0 + r) * 32 + (c0 >> 1)) = o;
    }
}

// ---------------- Pull-mode aggregation ----------------

// Layer 1: hs rows = 128 fp8 (64 ushorts). out (a1) packed bf16 (64 uints/row).
__global__ __launch_bounds__(256) void k_agg_relu(const unsigned short* __restrict__ hs,
                                                  const float* __restrict__ dinv,
                                                  const int* __restrict__ row_ptr,
                                                  const int* __restrict__ col,
                                                  const float* __restrict__ bias,
                                                  unsigned* __restrict__ out, int n) {
    int node = blockIdx.x * 4 + (threadIdx.x >> 6);
    if (node >= n) return;
    int lane = threadIdx.x & 63;
    float2 self = fp8x2_to_f32(hs[(size_t)node * 64 + lane]);
    float ax = self.x, ay = self.y;
    int p0 = row_ptr[node], p1 = row_ptr[node + 1];
    for (int base = p0; base < p1; base += 64) {
        int nb = min(64, p1 - base);
        int myc = col[base + min(lane, nb - 1)];
        int k = 0;
        for (; k + 4 <= nb; k += 4) {
            int j0 = __shfl(myc, k);
            int j1 = __shfl(myc, k + 1);
            int j2 = __shfl(myc, k + 2);
            int j3 = __shfl(myc, k + 3);
            unsigned v0 = hs[(size_t)j0 * 64 + lane];
            unsigned v1 = hs[(size_t)j1 * 64 + lane];
            unsigned v2 = hs[(size_t)j2 * 64 + lane];
            unsigned v3 = hs[(size_t)j3 * 64 + lane];
            float2 f0 = fp8x2_to_f32(v0);
            float2 f1 = fp8x2_to_f32(v1);
            float2 f2 = fp8x2_to_f32(v2);
            float2 f3 = fp8x2_to_f32(v3);
            ax += (f0.x + f1.x) + (f2.x + f3.x);
            ay += (f0.y + f1.y) + (f2.y + f3.y);
        }
        for (; k < nb; ++k) {
            int j = __shfl(myc, k);
            float2 f = fp8x2_to_f32(hs[(size_t)j * 64 + lane]);
            ax += f.x;
            ay += f.y;
        }
    }
    float di = dinv[node];
    ax = fmaf(di, ax, bias[2 * lane]);
    ay = fmaf(di, ay, bias[2 * lane + 1]);
    ax = ax > 0.f ? ax : 0.f;
    ay = ay > 0.f ? ay : 0.f;
    out[(size_t)node * 64 + lane] = pack_bf16x2(ax, ay);
}

// Layer 2: hs rows = 64 bf16 (ushort), lane = col. Fused log_softmax.
__global__ __launch_bounds__(256) void k_agg_lsm(const unsigned short* __restrict__ hs,
                                                 const float* __restrict__ dinv,
                                                 const int* __restrict__ row_ptr,
                                                 const int* __restrict__ col,
                                                 const float* __restrict__ bias,
                                                 float* __restrict__ out, int n) {
    int node = blockIdx.x * 4 + (threadIdx.x >> 6);
    if (node >= n) return;
    int lane = threadIdx.x & 63;
    float acc = __uint_as_float(((unsigned)hs[(size_t)node * 64 + lane]) << 16);
    int p0 = row_ptr[node], p1 = row_ptr[node + 1];
    for (int base = p0; base < p1; base += 64) {
        int nb = min(64, p1 - base);
        int myc = col[base + min(lane, nb - 1)];
        int k = 0;
        for (; k + 4 <= nb; k += 4) {
            int j0 = __shfl(myc, k);
            int j1 = __shfl(myc, k + 1);
            int j2 = __shfl(myc, k + 2);
            int j3 = __shfl(myc, k + 3);
            float v0 = __uint_as_float(((unsigned)hs[(size_t)j0 * 64 + lane]) << 16);
            float v1 = __uint_as_float(((unsigned)hs[(size_t)j1 * 64 + lane]) << 16);
            float v2 = __uint_as_float(((unsigned)hs[(size_t)j2 * 64 + lane]) << 16);
            float v3 = __uint_as_float(((unsigned)hs[(size_t)j3 * 64 + lane]) << 16);
            acc += (v0 + v1) + (v2 + v3);
        }
        for (; k < nb; ++k) {
            int j = __shfl(myc, k);
            acc += __uint_as_float(((unsigned)hs[(size_t)j * 64 + lane]) << 16);
        }
    }
    float v = fmaf(dinv[node], acc, bias[lane]);
    float m = v;
    for (int off = 32; off; off >>= 1) m = fmaxf(m, __shfl_xor(m, off));
    float e = __expf(v - m);
    float s = e;
    for (int off = 32; off; off >>= 1) s += __shfl_xor(s, off);
    out[(size_t)node * 64 + lane] = v - m - __logf(s);
}

// ---------------- launcher ----------------

extern "C" void kernel_launch(void* const* d_in, const int* in_sizes, int n_in,
                              void* d_out, int out_size, void* d_ws, size_t ws_size,
                              hipStream_t stream) {
    const float* x  = (const float*)d_in[0];
    const int*   ei = (const int*)d_in[1];
    const float* W1 = (const float*)d_in[2];
    const float* b1 = (const float*)d_in[3];
    const float* W2 = (const float*)d_in[4];
    const float* b2 = (const float*)d_in[5];
    float* out = (float*)d_out;

    const int N = in_sizes[0] / 128;   // 100000
    const int E = in_sizes[1] / 2;     // 1600000
    const int* src = ei;
    const int* dst = ei + E;
    const int npp = (N + NPART - 1) / NPART;  // 12500 (<= NPP_MAX)

    // workspace carve (256B aligned)
    char* w = (char*)d_ws;
    size_t off = 0;
    auto alloc = [&](size_t bytes) -> void* {
        void* p = w + off;
        off += (bytes + 255) & ~(size_t)255;
        return p;
    };
    int*      indeg    = (int*)alloc((size_t)N * 4);
    int*      row_ptr  = (int*)alloc((size_t)(N + 1) * 4);
    int*      colarr   = (int*)alloc((size_t)E * 4);
    int*      partials = (int*)alloc(256 * 4);
    int*      bmeta    = (int*)alloc(16 * 4);  // [0..7]=count, [8..15]=cursor
    int*      bbase    = (int*)alloc(NPART * 4);
    float*    dinv     = (float*)alloc((size_t)N * 4);
    unsigned* h1f8     = (unsigned*)alloc((size_t)N * 32 * 4);  // fp8 X@W1 scaled (128B/row)
    unsigned* a1b      = (unsigned*)alloc((size_t)N * 64 * 4);  // bf16 relu out
    unsigned* h2b      = (unsigned*)alloc((size_t)N * 32 * 4);  // bf16 a1@W2 scaled
    // CSR-build temporaries overlay a1b (dead until agg_relu): pairs + counts
    int2* pairs  = (int2*)a1b;                                  // E*8 = 12.8 MB
    int*  cntarr = (int*)((char*)a1b + (size_t)E * 8);          // 8*32*npp*4 = 12.8 MB
    (void)ws_size; (void)n_in; (void)out_size;

    int* bucketCount  = bmeta;
    int* bucketCursor = bmeta + 8;
    int nscan = (N + 1023) / 1024;
    int nA3 = (E + 4095) / 4096;

    k_zero16<<<1, 64, 0, stream>>>(bmeta);
    k_bcount<<<256, 256, 0, stream>>>(dst, bucketCount, E, npp);
    k_bscan<<<1, 64, 0, stream>>>(bucketCount, bbase, bucketCursor);
    k_bucket<<<nA3, 256, 0, stream>>>(src, dst, bucketCursor, pairs, E, npp);
    k_count_part<<<NPART * KB, 256, 0, stream>>>(pairs, bbase, bucketCount, cntarr, npp);
    k_indeg<<<(N + 255) / 256, 256, 0, stream>>>(cntarr, indeg, N, npp);
    k_scan_local<<<nscan, 256, 0, stream>>>(indeg, row_ptr, partials, N);
    k_scan_partials<<<1, 256, 0, stream>>>(partials, nscan);
    k_finalize<<<(N + 255) / 256, 256, 0, stream>>>(row_ptr, partials, indeg, dinv, N, E);
    k_bases<<<(N + 255) / 256, 256, 0, stream>>>(cntarr, row_ptr, N, npp);
    k_fill2<<<NPART * KB, 256, 0, stream>>>(pairs, bbase, bucketCount, cntarr,
                                            colarr, npp);

    k_gemm128<<<N / 32, 256, 0, stream>>>(x, W1, dinv, h1f8);
    k_agg_relu<<<(N + 3) / 4, 256, 0, stream>>>((const unsigned short*)h1f8, dinv,
                                                row_ptr, colarr, b1, a1b, N);
    k_gemm64<<<N / 32, 256, 0, stream>>>(a1b, W2, dinv, h2b);
    k_agg_lsm<<<(N + 3) / 4, 256, 0, stream>>>((const unsigned short*)h2b, dinv,
                                               row_ptr, colarr, b2, out, N);
}

// Round 10
// 333.107 us; speedup vs baseline: 1.1072x; 1.0189x over previous
//
#include <hip/hip_runtime.h>
#include <hip/hip_fp16.h>
#include <cstdint>
#include <cstddef>
#include <cstring>

// ---------------- bf16 pack/unpack helpers (RNE) ----------------

__device__ inline unsigned pack_bf16x2(float a, float b) {
    unsigned ua = __float_as_uint(a);
    unsigned ub = __float_as_uint(b);
    ua += 0x7fffu + ((ua >> 16) & 1u);
    ub += 0x7fffu + ((ub >> 16) & 1u);
    return (ua >> 16) | (ub & 0xffff0000u);
}
__device__ inline float bf16lo(unsigned u) { return __uint_as_float(u << 16); }
__device__ inline float bf16hi(unsigned u) { return __uint_as_float(u & 0xffff0000u); }

// ---------------- fp8 (OCP e4m3fn) pack/unpack ----------------

typedef float fv2 __attribute__((ext_vector_type(2)));

// Decode 2 fp8 from word (HI=false: bytes 0-1, HI=true: bytes 2-3).
// NOTE: the builtin's word-half selector must be a literal -> template param.
template <bool HI>
__device__ inline float2 fp8x2_to_f32_sel(unsigned u) {
#if __has_builtin(__builtin_amdgcn_cvt_pk_f32_fp8)
    fv2 r = __builtin_amdgcn_cvt_pk_f32_fp8((int)u, HI);
    return make_float2(r.x, r.y);
#else
    unsigned u2 = HI ? (u >> 16) : (u & 0xffffu);
    unsigned w = (u2 & 0xFFu) | ((u2 & 0xFF00u) << 8);
    unsigned hb = ((w & 0x00800080u) << 8) | ((w & 0x007f007fu) << 7);
    __half2 h2;
    memcpy(&h2, &hb, 4);
    float2 f = __half22float2(h2);
    f.x *= 256.0f;
    f.y *= 256.0f;
    return f;
#endif
}

__device__ inline unsigned f32_to_fp8_byte(float v) {  // fallback helper
    unsigned short hb = __half_as_ushort(__float2half(v * 0.00390625f));  // v/256
    unsigned t = hb & 0x7fffu;
    t += 0x3fu + ((t >> 7) & 1u);  // RNE on the 7 dropped mantissa bits
    return ((hb >> 8) & 0x80u) | (t >> 7);
}

__device__ inline unsigned pack4_fp8(float a0, float a1, float a2, float a3) {
#if __has_builtin(__builtin_amdgcn_cvt_pk_fp8_f32)
    int u = __builtin_amdgcn_cvt_pk_fp8_f32(a0, a1, 0, false);
    u = __builtin_amdgcn_cvt_pk_fp8_f32(a2, a3, u, true);
    return (unsigned)u;
#else
    return f32_to_fp8_byte(a0) | (f32_to_fp8_byte(a1) << 8) |
           (f32_to_fp8_byte(a2) << 16) | (f32_to_fp8_byte(a3) << 24);
#endif
}

typedef int iv4 __attribute__((ext_vector_type(4)));

#define NPART 8      // dst-partitions == XCDs (blockIdx%8 locality heuristic)
#define KB    32     // blocks per partition in count/fill passes
#define NPP_MAX 12500

// ---------------- CSR build: atomic-free counting-sort pipeline ----------------

__global__ void k_zero16(int* __restrict__ p) {
    if (threadIdx.x < 16) p[threadIdx.x] = 0;
}

__global__ __launch_bounds__(256) void k_bcount(const int* __restrict__ dst,
                                                int* __restrict__ bucketCount,
                                                int E, int npp) {
    __shared__ int c8[NPART];
    if (threadIdx.x < NPART) c8[threadIdx.x] = 0;
    __syncthreads();
    int t = blockIdx.x * blockDim.x + threadIdx.x;
    int stride = gridDim.x * blockDim.x;
    int E4 = E >> 2;
    const iv4* d4 = (const iv4*)dst;
    for (int i = t; i < E4; i += stride) {
        iv4 d = d4[i];
        atomicAdd(&c8[(unsigned)d.x / (unsigned)npp], 1);
        atomicAdd(&c8[(unsigned)d.y / (unsigned)npp], 1);
        atomicAdd(&c8[(unsigned)d.z / (unsigned)npp], 1);
        atomicAdd(&c8[(unsigned)d.w / (unsigned)npp], 1);
    }
    for (int e = E4 * 4 + t; e < E; e += stride)
        atomicAdd(&c8[(unsigned)dst[e] / (unsigned)npp], 1);
    __syncthreads();
    if (threadIdx.x < NPART) atomicAdd(&bucketCount[threadIdx.x], c8[threadIdx.x]);
}

__global__ void k_bscan(const int* __restrict__ bucketCount,
                        int* __restrict__ bucketBase,
                        int* __restrict__ bucketCursor) {
    if (threadIdx.x == 0) {
        int run = 0;
        for (int p = 0; p < NPART; ++p) {
            bucketBase[p] = run;
            bucketCursor[p] = run;
            run += bucketCount[p];
        }
    }
}

__global__ __launch_bounds__(256) void k_bucket(const int* __restrict__ src,
                                                const int* __restrict__ dst,
                                                int* __restrict__ bucketCursor,
                                                int2* __restrict__ pairs,
                                                int E, int npp) {
    __shared__ int cnt8[NPART], run8[NPART], gbase8[NPART];
    int tid = threadIdx.x;
    int base_e = blockIdx.x * 4096 + tid * 16;
    int nv = min(16, E - base_e);
    if (nv < 0) nv = 0;
    int dv[16], sv[16];
    if (nv == 16) {
        for (int q = 0; q < 4; ++q) {
            iv4 d = *(const iv4*)(dst + base_e + q * 4);
            iv4 s = *(const iv4*)(src + base_e + q * 4);
            dv[q * 4 + 0] = d.x; dv[q * 4 + 1] = d.y; dv[q * 4 + 2] = d.z; dv[q * 4 + 3] = d.w;
            sv[q * 4 + 0] = s.x; sv[q * 4 + 1] = s.y; sv[q * 4 + 2] = s.z; sv[q * 4 + 3] = s.w;
        }
    } else {
        for (int k = 0; k < nv; ++k) { dv[k] = dst[base_e + k]; sv[k] = src[base_e + k]; }
    }
    if (tid < NPART) { cnt8[tid] = 0; run8[tid] = 0; }
    __syncthreads();
    for (int k = 0; k < nv; ++k)
        atomicAdd(&cnt8[(unsigned)dv[k] / (unsigned)npp], 1);
    __syncthreads();
    if (tid < NPART) gbase8[tid] = atomicAdd(&bucketCursor[tid], cnt8[tid]);
    __syncthreads();
    for (int k = 0; k < nv; ++k) {
        int p = (unsigned)dv[k] / (unsigned)npp;
        int r = atomicAdd(&run8[p], 1);
        int2 pr; pr.x = dv[k]; pr.y = sv[k];
        pairs[gbase8[p] + r] = pr;
    }
}

__global__ __launch_bounds__(256) void k_count_part(const int2* __restrict__ pairs,
                                                    const int* __restrict__ bucketBase,
                                                    const int* __restrict__ bucketCount,
                                                    int* __restrict__ cntarr, int npp) {
    __shared__ int h[NPP_MAX];
    int p = blockIdx.x & (NPART - 1);
    int b = blockIdx.x >> 3;
    int lo = p * npp;
    for (int i = threadIdx.x; i < npp; i += 256) h[i] = 0;
    __syncthreads();
    int segBase = bucketBase[p], sz = bucketCount[p];
    int chunk = (sz + KB - 1) / KB;
    int s0 = segBase + b * chunk;
    int s1 = min(segBase + sz, s0 + chunk);
    for (int i = s0 + threadIdx.x; i < s1; i += 256)
        atomicAdd(&h[pairs[i].x - lo], 1);
    __syncthreads();
    size_t out = (size_t)(p * KB + b) * npp;
    for (int i = threadIdx.x; i < npp; i += 256) cntarr[out + i] = h[i];
}

__global__ void k_indeg(const int* __restrict__ cntarr, int* __restrict__ indeg,
                        int n, int npp) {
    int d = blockIdx.x * blockDim.x + threadIdx.x;
    if (d >= n) return;
    int p = (unsigned)d / (unsigned)npp;
    int dl = d - p * npp;
    size_t base = (size_t)p * KB * npp + dl;
    int s = 0;
    for (int b = 0; b < KB; ++b) s += cntarr[base + (size_t)b * npp];
    indeg[d] = s;
}

__global__ void k_scan_local(const int* __restrict__ in, int* __restrict__ out,
                             int* __restrict__ partials, int n) {
    __shared__ int s[256];
    int t = threadIdx.x;
    int base = blockIdx.x * 1024 + t * 4;
    int v0 = (base + 0) < n ? in[base + 0] : 0;
    int v1 = (base + 1) < n ? in[base + 1] : 0;
    int v2 = (base + 2) < n ? in[base + 2] : 0;
    int v3 = (base + 3) < n ? in[base + 3] : 0;
    int sum = v0 + v1 + v2 + v3;
    s[t] = sum;
    __syncthreads();
    for (int off = 1; off < 256; off <<= 1) {
        int x = (t >= off) ? s[t - off] : 0;
        __syncthreads();
        s[t] += x;
        __syncthreads();
    }
    int excl = s[t] - sum;
    if ((base + 0) < n) out[base + 0] = excl;
    if ((base + 1) < n) out[base + 1] = excl + v0;
    if ((base + 2) < n) out[base + 2] = excl + v0 + v1;
    if ((base + 3) < n) out[base + 3] = excl + v0 + v1 + v2;
    if (t == 255) partials[blockIdx.x] = s[255];
}

__global__ void k_scan_partials(int* __restrict__ partials, int np) {
    __shared__ int s[256];
    int t = threadIdx.x;
    int v = (t < np) ? partials[t] : 0;
    s[t] = v;
    __syncthreads();
    for (int off = 1; off < 256; off <<= 1) {
        int x = (t >= off) ? s[t - off] : 0;
        __syncthreads();
        s[t] += x;
        __syncthreads();
    }
    if (t < np) partials[t] = s[t] - v;
}

__global__ void k_finalize(int* __restrict__ row_ptr, const int* __restrict__ partials,
                           const int* __restrict__ indeg, float* __restrict__ dinv,
                           int n, int E) {
    int i = blockIdx.x * blockDim.x + threadIdx.x;
    if (i < n) {
        int rp = row_ptr[i] + partials[i >> 10];
        row_ptr[i] = rp;
        dinv[i] = rsqrtf((float)indeg[i] + 1.0f);  // +1 = self loop
        if (i == 0) row_ptr[n] = E;
    }
}

__global__ void k_bases(int* __restrict__ cntarr, const int* __restrict__ row_ptr,
                        int n, int npp) {
    int d = blockIdx.x * blockDim.x + threadIdx.x;
    if (d >= n) return;
    int p = (unsigned)d / (unsigned)npp;
    int dl = d - p * npp;
    size_t base = (size_t)p * KB * npp + dl;
    int run = row_ptr[d];
    for (int b = 0; b < KB; ++b) {
        size_t idx = base + (size_t)b * npp;
        int c = cntarr[idx];
        cntarr[idx] = run;
        run += c;
    }
}

__global__ __launch_bounds__(256) void k_fill2(const int2* __restrict__ pairs,
                                               const int* __restrict__ bucketBase,
                                               const int* __restrict__ bucketCount,
                                               const int* __restrict__ cntarr,
                                               int* __restrict__ col, int npp) {
    __shared__ int cur[NPP_MAX];
    int p = blockIdx.x & (NPART - 1);
    int b = blockIdx.x >> 3;
    int lo = p * npp;
    size_t slice = (size_t)(p * KB + b) * npp;
    for (int i = threadIdx.x; i < npp; i += 256) cur[i] = cntarr[slice + i];
    __syncthreads();
    int segBase = bucketBase[p], sz = bucketCount[p];
    int chunk = (sz + KB - 1) / KB;
    int s0 = segBase + b * chunk;
    int s1 = min(segBase + sz, s0 + chunk);
    for (int i = s0 + threadIdx.x; i < s1; i += 256) {
        int2 e = pairs[i];
        int pos = atomicAdd(&cur[e.x - lo], 1);
        col[pos] = e.y;
    }
}

// ---------------- GEMMs — epilogue: row *= dinv[row], store fp8 / bf16 ----------

// Hf8[N x 32 uints] = fp8x4( dinv[row] * (X @ W1) ); X fp32.
__global__ __launch_bounds__(256) void k_gemm128(const float* __restrict__ X,
                                                 const float* __restrict__ W,
                                                 const float* __restrict__ dinv,
                                                 unsigned* __restrict__ Hf8) {
    __shared__ float Wl[32 * 128];
    __shared__ float Xs[32 * 32];
    int t = threadIdx.x;
    size_t row0 = (size_t)blockIdx.x * 32;
    int r0 = (t >> 5) * 4;
    int c0 = (t & 31) * 4;
    int lr = t >> 3, lk = (t & 7) * 4;
    float acc[4][4] = {};
    for (int kc = 0; kc < 128; kc += 32) {
        __syncthreads();
        for (int idx = t; idx < 1024; idx += 256)
            ((float4*)Wl)[idx] = ((const float4*)W)[kc * 32 + idx];
        *(float4*)(Xs + lr * 32 + lk) =
            *(const float4*)(X + (row0 + lr) * 128 + kc + lk);
        __syncthreads();
        for (int kk = 0; kk < 32; kk += 4) {
            float a[4][4], wv[4][4];
            for (int r = 0; r < 4; r++) {
                float4 av = *(const float4*)(Xs + (r0 + r) * 32 + kk);
                a[r][0] = av.x; a[r][1] = av.y; a[r][2] = av.z; a[r][3] = av.w;
            }
            for (int j = 0; j < 4; j++) {
                float4 wq = *(const float4*)(Wl + (kk + j) * 128 + c0);
                wv[j][0] = wq.x; wv[j][1] = wq.y; wv[j][2] = wq.z; wv[j][3] = wq.w;
            }
            for (int r = 0; r < 4; r++)
                for (int j = 0; j < 4; j++)
                    for (int c = 0; c < 4; c++)
                        acc[r][c] += a[r][j] * wv[j][c];
        }
    }
    for (int r = 0; r < 4; r++) {
        float di = dinv[row0 + r0 + r];
        Hf8[(row0 + r0 + r) * 32 + (c0 >> 2)] =
            pack4_fp8(di * acc[r][0], di * acc[r][1], di * acc[r][2], di * acc[r][3]);
    }
}

// Hb[N x 32 uints] = bf16x2( dinv[row] * (A1 @ W2) ); A1 is packed bf16 (64 uints/row).
__global__ __launch_bounds__(256) void k_gemm64(const unsigned* __restrict__ Xb,
                                                const float* __restrict__ W,
                                                const float* __restrict__ dinv,
                                                unsigned* __restrict__ Hb) {
    __shared__ float Wl[32 * 64];
    __shared__ float Xs[32 * 32];
    int t = threadIdx.x;
    size_t row0 = (size_t)blockIdx.x * 32;
    int r0 = (t >> 4) * 2;
    int c0 = (t & 15) * 4;
    int lr = t >> 3, lk = (t & 7) * 4;
    float acc[2][4] = {};
    for (int kc = 0; kc < 128; kc += 32) {
        __syncthreads();
        ((float4*)Wl)[t]       = ((const float4*)W)[kc * 16 + t];
        ((float4*)Wl)[t + 256] = ((const float4*)W)[kc * 16 + t + 256];
        {
            uint2 u = *(const uint2*)(Xb + (row0 + lr) * 64 + ((kc + lk) >> 1));
            float4 xv = {bf16lo(u.x), bf16hi(u.x), bf16lo(u.y), bf16hi(u.y)};
            *(float4*)(Xs + lr * 32 + lk) = xv;
        }
        __syncthreads();
        for (int kk = 0; kk < 32; kk += 4) {
            float a[2][4], wv[4][4];
            for (int r = 0; r < 2; r++) {
                float4 av = *(const float4*)(Xs + (r0 + r) * 32 + kk);
                a[r][0] = av.x; a[r][1] = av.y; a[r][2] = av.z; a[r][3] = av.w;
            }
            for (int j = 0; j < 4; j++) {
                float4 wq = *(const float4*)(Wl + (kk + j) * 64 + c0);
                wv[j][0] = wq.x; wv[j][1] = wq.y; wv[j][2] = wq.z; wv[j][3] = wq.w;
            }
            for (int r = 0; r < 2; r++)
                for (int j = 0; j < 4; j++)
                    for (int c = 0; c < 4; c++)
                        acc[r][c] += a[r][j] * wv[j][c];
        }
    }
    for (int r = 0; r < 2; r++) {
        float di = dinv[row0 + r0 + r];
        uint2 o = {pack_bf16x2(di * acc[r][0], di * acc[r][1]),
                   pack_bf16x2(di * acc[r][2], di * acc[r][3])};
        *(uint2*)(Hb + (row0 + r0 + r) * 32 + (c0 >> 1)) = o;
    }
}

// ---------------- Pull-mode aggregation: half-wave per neighbor ----------------
// Lanes 0-31 process even-k neighbors, lanes 32-63 odd-k, in one instruction
// stream (1 load instr / 2 edges). Partials combined via shfl_xor(32).

// Layer 1: hs rows = 32 uints (128 fp8). Lane owns cols 4l..4l+3.
// out (a1) packed bf16 (64 uints/row).
__global__ __launch_bounds__(256) void k_agg_relu(const unsigned* __restrict__ hs,
                                                  const float* __restrict__ dinv,
                                                  const int* __restrict__ row_ptr,
                                                  const int* __restrict__ col,
                                                  const float* __restrict__ bias,
                                                  unsigned* __restrict__ out, int n) {
    int node = blockIdx.x * 4 + (threadIdx.x >> 6);
    if (node >= n) return;
    int lane = threadIdx.x & 63;
    int half = lane >> 5;
    int l = lane & 31;
    float a0 = 0.f, a1 = 0.f, a2 = 0.f, a3 = 0.f;
    if (half == 0) {  // self term counted once
        unsigned u = hs[(size_t)node * 32 + l];
        float2 f01 = fp8x2_to_f32_sel<false>(u);
        float2 f23 = fp8x2_to_f32_sel<true>(u);
        a0 = f01.x; a1 = f01.y; a2 = f23.x; a3 = f23.y;
    }
    int p0 = row_ptr[node], p1 = row_ptr[node + 1];
    for (int base = p0; base < p1; base += 64) {
        int nb = min(64, p1 - base);
        int myc = col[base + min(lane, nb - 1)];
        int k = 0;
        for (; k + 8 <= nb; k += 8) {  // 8 edges, 4 independent loads
            int jA = __shfl(myc, k + half);
            int jB = __shfl(myc, k + 2 + half);
            int jC = __shfl(myc, k + 4 + half);
            int jD = __shfl(myc, k + 6 + half);
            unsigned uA = hs[(size_t)jA * 32 + l];
            unsigned uB = hs[(size_t)jB * 32 + l];
            unsigned uC = hs[(size_t)jC * 32 + l];
            unsigned uD = hs[(size_t)jD * 32 + l];
            float2 fA0 = fp8x2_to_f32_sel<false>(uA), fA1 = fp8x2_to_f32_sel<true>(uA);
            float2 fB0 = fp8x2_to_f32_sel<false>(uB), fB1 = fp8x2_to_f32_sel<true>(uB);
            float2 fC0 = fp8x2_to_f32_sel<false>(uC), fC1 = fp8x2_to_f32_sel<true>(uC);
            float2 fD0 = fp8x2_to_f32_sel<false>(uD), fD1 = fp8x2_to_f32_sel<true>(uD);
            a0 += (fA0.x + fB0.x) + (fC0.x + fD0.x);
            a1 += (fA0.y + fB0.y) + (fC0.y + fD0.y);
            a2 += (fA1.x + fB1.x) + (fC1.x + fD1.x);
            a3 += (fA1.y + fB1.y) + (fC1.y + fD1.y);
        }
        for (; k < nb; k += 2) {
            int kk = k + half;
            if (kk < nb) {
                int j = __shfl(myc, kk);
                unsigned u = hs[(size_t)j * 32 + l];
                float2 f0 = fp8x2_to_f32_sel<false>(u);
                float2 f1 = fp8x2_to_f32_sel<true>(u);
                a0 += f0.x; a1 += f0.y; a2 += f1.x; a3 += f1.y;
            }
        }
    }
    // combine halves
    a0 += __shfl_xor(a0, 32);
    a1 += __shfl_xor(a1, 32);
    a2 += __shfl_xor(a2, 32);
    a3 += __shfl_xor(a3, 32);
    float di = dinv[node];
    if (half == 0) {
        float4 b4 = *(const float4*)(bias + 4 * l);
        a0 = fmaf(di, a0, b4.x);
        a1 = fmaf(di, a1, b4.y);
        a2 = fmaf(di, a2, b4.z);
        a3 = fmaf(di, a3, b4.w);
        a0 = a0 > 0.f ? a0 : 0.f;
        a1 = a1 > 0.f ? a1 : 0.f;
        a2 = a2 > 0.f ? a2 : 0.f;
        a3 = a3 > 0.f ? a3 : 0.f;
        uint2 o = {pack_bf16x2(a0, a1), pack_bf16x2(a2, a3)};
        *(uint2*)(out + (size_t)node * 64 + 2 * l) = o;
    }
}

// Layer 2: hs rows = 32 uints (64 bf16). Lane owns cols 2l, 2l+1. Fused log_softmax.
__global__ __launch_bounds__(256) void k_agg_lsm(const unsigned* __restrict__ hs,
                                                 const float* __restrict__ dinv,
                                                 const int* __restrict__ row_ptr,
                                                 const int* __restrict__ col,
                                                 const float* __restrict__ bias,
                                                 float* __restrict__ out, int n) {
    int node = blockIdx.x * 4 + (threadIdx.x >> 6);
    if (node >= n) return;
    int lane = threadIdx.x & 63;
    int half = lane >> 5;
    int l = lane & 31;
    float ax = 0.f, ay = 0.f;
    if (half == 0) {
        unsigned u = hs[(size_t)node * 32 + l];
        ax = bf16lo(u);
        ay = bf16hi(u);
    }
    int p0 = row_ptr[node], p1 = row_ptr[node + 1];
    for (int base = p0; base < p1; base += 64) {
        int nb = min(64, p1 - base);
        int myc = col[base + min(lane, nb - 1)];
        int k = 0;
        for (; k + 8 <= nb; k += 8) {
            int jA = __shfl(myc, k + half);
            int jB = __shfl(myc, k + 2 + half);
            int jC = __shfl(myc, k + 4 + half);
            int jD = __shfl(myc, k + 6 + half);
            unsigned uA = hs[(size_t)jA * 32 + l];
            unsigned uB = hs[(size_t)jB * 32 + l];
            unsigned uC = hs[(size_t)jC * 32 + l];
            unsigned uD = hs[(size_t)jD * 32 + l];
            ax += (bf16lo(uA) + bf16lo(uB)) + (bf16lo(uC) + bf16lo(uD));
            ay += (bf16hi(uA) + bf16hi(uB)) + (bf16hi(uC) + bf16hi(uD));
        }
        for (; k < nb; k += 2) {
            int kk = k + half;
            if (kk < nb) {
                int j = __shfl(myc, kk);
                unsigned u = hs[(size_t)j * 32 + l];
                ax += bf16lo(u);
                ay += bf16hi(u);
            }
        }
    }
    ax += __shfl_xor(ax, 32);
    ay += __shfl_xor(ay, 32);
    float di = dinv[node];
    float2 b2 = ((const float2*)bias)[l];
    float vx = fmaf(di, ax, b2.x);
    float vy = fmaf(di, ay, b2.y);
    // softmax over 64 values: 2/lane across the 32-lane half (both halves mirror)
    float m = fmaxf(vx, vy);
    for (int off = 16; off; off >>= 1) m = fmaxf(m, __shfl_xor(m, off));
    float s = __expf(vx - m) + __expf(vy - m);
    for (int off = 16; off; off >>= 1) s += __shfl_xor(s, off);
    float ls = __logf(s);
    if (half == 0) {
        float2 o = {vx - m - ls, vy - m - ls};
        ((float2*)(out + (size_t)node * 64))[l] = o;
    }
}

// ---------------- launcher ----------------

extern "C" void kernel_launch(void* const* d_in, const int* in_sizes, int n_in,
                              void* d_out, int out_size, void* d_ws, size_t ws_size,
                              hipStream_t stream) {
    const float* x  = (const float*)d_in[0];
    const int*   ei = (const int*)d_in[1];
    const float* W1 = (const float*)d_in[2];
    const float* b1 = (const float*)d_in[3];
    const float* W2 = (const float*)d_in[4];
    const float* b2 = (const float*)d_in[5];
    float* out = (float*)d_out;

    const int N = in_sizes[0] / 128;   // 100000
    const int E = in_sizes[1] / 2;     // 1600000
    const int* src = ei;
    const int* dst = ei + E;
    const int npp = (N + NPART - 1) / NPART;  // 12500 (<= NPP_MAX)

    // workspace carve (256B aligned)
    char* w = (char*)d_ws;
    size_t off = 0;
    auto alloc = [&](size_t bytes) -> void* {
        void* p = w + off;
        off += (bytes + 255) & ~(size_t)255;
        return p;
    };
    int*      indeg    = (int*)alloc((size_t)N * 4);
    int*      row_ptr  = (int*)alloc((size_t)(N + 1) * 4);
    int*      colarr   = (int*)alloc((size_t)E * 4);
    int*      partials = (int*)alloc(256 * 4);
    int*      bmeta    = (int*)alloc(16 * 4);  // [0..7]=count, [8..15]=cursor
    int*      bbase    = (int*)alloc(NPART * 4);
    float*    dinv     = (float*)alloc((size_t)N * 4);
    unsigned* h1f8     = (unsigned*)alloc((size_t)N * 32 * 4);  // fp8 X@W1 scaled (128B/row)
    unsigned* a1b      = (unsigned*)alloc((size_t)N * 64 * 4);  // bf16 relu out
    unsigned* h2b      = (unsigned*)alloc((size_t)N * 32 * 4);  // bf16 a1@W2 scaled
    // CSR-build temporaries overlay a1b (dead until agg_relu): pairs + counts
    int2* pairs  = (int2*)a1b;                                  // E*8 = 12.8 MB
    int*  cntarr = (int*)((char*)a1b + (size_t)E * 8);          // 8*32*npp*4 = 12.8 MB
    (void)ws_size; (void)n_in; (void)out_size;

    int* bucketCount  = bmeta;
    int* bucketCursor = bmeta + 8;
    int nscan = (N + 1023) / 1024;
    int nA3 = (E + 4095) / 4096;

    k_zero16<<<1, 64, 0, stream>>>(bmeta);
    k_bcount<<<256, 256, 0, stream>>>(dst, bucketCount, E, npp);
    k_bscan<<<1, 64, 0, stream>>>(bucketCount, bbase, bucketCursor);
    k_bucket<<<nA3, 256, 0, stream>>>(src, dst, bucketCursor, pairs, E, npp);
    k_count_part<<<NPART * KB, 256, 0, stream>>>(pairs, bbase, bucketCount, cntarr, npp);
    k_indeg<<<(N + 255) / 256, 256, 0, stream>>>(cntarr, indeg, N, npp);
    k_scan_local<<<nscan, 256, 0, stream>>>(indeg, row_ptr, partials, N);
    k_scan_partials<<<1, 256, 0, stream>>>(partials, nscan);
    k_finalize<<<(N + 255) / 256, 256, 0, stream>>>(row_ptr, partials, indeg, dinv, N, E);
    k_bases<<<(N + 255) / 256, 256, 0, stream>>>(cntarr, row_ptr, N, npp);
    k_fill2<<<NPART * KB, 256, 0, stream>>>(pairs, bbase, bucketCount, cntarr,
                                            colarr, npp);

    k_gemm128<<<N / 32, 256, 0, stream>>>(x, W1, dinv, h1f8);
    k_agg_relu<<<(N + 3) / 4, 256, 0, stream>>>(h1f8, dinv, row_ptr, colarr, b1, a1b, N);
    k_gemm64<<<N / 32, 256, 0, stream>>>(a1b, W2, dinv, h2b);
    k_agg_lsm<<<(N + 3) / 4, 256, 0, stream>>>(h2b, dinv, row_ptr, colarr, b2, out, N);
}

// Round 11
// 306.809 us; speedup vs baseline: 1.2021x; 1.0857x over previous
//
#include <hip/hip_runtime.h>
#include <hip/hip_fp16.h>
#include <cstdint>
#include <cstddef>
#include <cstring>

// ---------------- bf16 pack/unpack helpers (RNE) ----------------

__device__ inline unsigned pack_bf16x2(float a, float b) {
    unsigned ua = __float_as_uint(a);
    unsigned ub = __float_as_uint(b);
    ua += 0x7fffu + ((ua >> 16) & 1u);
    ub += 0x7fffu + ((ub >> 16) & 1u);
    return (ua >> 16) | (ub & 0xffff0000u);
}
__device__ inline unsigned short bf16_rne(float v) {
    unsigned u = __float_as_uint(v);
    u += 0x7fffu + ((u >> 16) & 1u);
    return (unsigned short)(u >> 16);
}
__device__ inline float bf16lo(unsigned u) { return __uint_as_float(u << 16); }
__device__ inline float bf16hi(unsigned u) { return __uint_as_float(u & 0xffff0000u); }

// ---------------- fp8 (OCP e4m3fn) pack/unpack ----------------

typedef float fv2 __attribute__((ext_vector_type(2)));

template <bool HI>
__device__ inline float2 fp8x2_to_f32_sel(unsigned u) {
#if __has_builtin(__builtin_amdgcn_cvt_pk_f32_fp8)
    fv2 r = __builtin_amdgcn_cvt_pk_f32_fp8((int)u, HI);
    return make_float2(r.x, r.y);
#else
    unsigned u2 = HI ? (u >> 16) : (u & 0xffffu);
    unsigned w = (u2 & 0xFFu) | ((u2 & 0xFF00u) << 8);
    unsigned hb = ((w & 0x00800080u) << 8) | ((w & 0x007f007fu) << 7);
    __half2 h2;
    memcpy(&h2, &hb, 4);
    float2 f = __half22float2(h2);
    f.x *= 256.0f;
    f.y *= 256.0f;
    return f;
#endif
}

__device__ inline unsigned f32_to_fp8_byte(float v) {  // fallback helper
    unsigned short hb = __half_as_ushort(__float2half(v * 0.00390625f));  // v/256
    unsigned t = hb & 0x7fffu;
    t += 0x3fu + ((t >> 7) & 1u);
    return ((hb >> 8) & 0x80u) | (t >> 7);
}

__device__ inline unsigned char f32_to_fp8_b(float v) {
#if __has_builtin(__builtin_amdgcn_cvt_pk_fp8_f32)
    return (unsigned char)(__builtin_amdgcn_cvt_pk_fp8_f32(v, v, 0, false) & 0xff);
#else
    return (unsigned char)f32_to_fp8_byte(v);
#endif
}

typedef int iv4 __attribute__((ext_vector_type(4)));

#define NPART 8
#define KB    32
#define NPP_MAX 12500

// ---------------- CSR build: atomic-free counting-sort pipeline ----------------

__global__ void k_zero16(int* __restrict__ p) {
    if (threadIdx.x < 16) p[threadIdx.x] = 0;
}

__global__ __launch_bounds__(256) void k_bcount(const int* __restrict__ dst,
                                                int* __restrict__ bucketCount,
                                                int E, int npp) {
    __shared__ int c8[NPART];
    if (threadIdx.x < NPART) c8[threadIdx.x] = 0;
    __syncthreads();
    int t = blockIdx.x * blockDim.x + threadIdx.x;
    int stride = gridDim.x * blockDim.x;
    int E4 = E >> 2;
    const iv4* d4 = (const iv4*)dst;
    for (int i = t; i < E4; i += stride) {
        iv4 d = d4[i];
        atomicAdd(&c8[(unsigned)d.x / (unsigned)npp], 1);
        atomicAdd(&c8[(unsigned)d.y / (unsigned)npp], 1);
        atomicAdd(&c8[(unsigned)d.z / (unsigned)npp], 1);
        atomicAdd(&c8[(unsigned)d.w / (unsigned)npp], 1);
    }
    for (int e = E4 * 4 + t; e < E; e += stride)
        atomicAdd(&c8[(unsigned)dst[e] / (unsigned)npp], 1);
    __syncthreads();
    if (threadIdx.x < NPART) atomicAdd(&bucketCount[threadIdx.x], c8[threadIdx.x]);
}

__global__ void k_bscan(const int* __restrict__ bucketCount,
                        int* __restrict__ bucketBase,
                        int* __restrict__ bucketCursor) {
    if (threadIdx.x == 0) {
        int run = 0;
        for (int p = 0; p < NPART; ++p) {
            bucketBase[p] = run;
            bucketCursor[p] = run;
            run += bucketCount[p];
        }
    }
}

__global__ __launch_bounds__(256) void k_bucket(const int* __restrict__ src,
                                                const int* __restrict__ dst,
                                                int* __restrict__ bucketCursor,
                                                int2* __restrict__ pairs,
                                                int E, int npp) {
    __shared__ int cnt8[NPART], run8[NPART], gbase8[NPART];
    int tid = threadIdx.x;
    int base_e = blockIdx.x * 4096 + tid * 16;
    int nv = min(16, E - base_e);
    if (nv < 0) nv = 0;
    int dv[16], sv[16];
    if (nv == 16) {
        for (int q = 0; q < 4; ++q) {
            iv4 d = *(const iv4*)(dst + base_e + q * 4);
            iv4 s = *(const iv4*)(src + base_e + q * 4);
            dv[q * 4 + 0] = d.x; dv[q * 4 + 1] = d.y; dv[q * 4 + 2] = d.z; dv[q * 4 + 3] = d.w;
            sv[q * 4 + 0] = s.x; sv[q * 4 + 1] = s.y; sv[q * 4 + 2] = s.z; sv[q * 4 + 3] = s.w;
        }
    } else {
        for (int k = 0; k < nv; ++k) { dv[k] = dst[base_e + k]; sv[k] = src[base_e + k]; }
    }
    if (tid < NPART) { cnt8[tid] = 0; run8[tid] = 0; }
    __syncthreads();
    for (int k = 0; k < nv; ++k)
        atomicAdd(&cnt8[(unsigned)dv[k] / (unsigned)npp], 1);
    __syncthreads();
    if (tid < NPART) gbase8[tid] = atomicAdd(&bucketCursor[tid], cnt8[tid]);
    __syncthreads();
    for (int k = 0; k < nv; ++k) {
        int p = (unsigned)dv[k] / (unsigned)npp;
        int r = atomicAdd(&run8[p], 1);
        int2 pr; pr.x = dv[k]; pr.y = sv[k];
        pairs[gbase8[p] + r] = pr;
    }
}

__global__ __launch_bounds__(256) void k_count_part(const int2* __restrict__ pairs,
                                                    const int* __restrict__ bucketBase,
                                                    const int* __restrict__ bucketCount,
                                                    int* __restrict__ cntarr, int npp) {
    __shared__ int h[NPP_MAX];
    int p = blockIdx.x & (NPART - 1);
    int b = blockIdx.x >> 3;
    int lo = p * npp;
    for (int i = threadIdx.x; i < npp; i += 256) h[i] = 0;
    __syncthreads();
    int segBase = bucketBase[p], sz = bucketCount[p];
    int chunk = (sz + KB - 1) / KB;
    int s0 = segBase + b * chunk;
    int s1 = min(segBase + sz, s0 + chunk);
    for (int i = s0 + threadIdx.x; i < s1; i += 256)
        atomicAdd(&h[pairs[i].x - lo], 1);
    __syncthreads();
    size_t out = (size_t)(p * KB + b) * npp;
    for (int i = threadIdx.x; i < npp; i += 256) cntarr[out + i] = h[i];
}

__global__ void k_indeg(const int* __restrict__ cntarr, int* __restrict__ indeg,
                        int n, int npp) {
    int d = blockIdx.x * blockDim.x + threadIdx.x;
    if (d >= n) return;
    int p = (unsigned)d / (unsigned)npp;
    int dl = d - p * npp;
    size_t base = (size_t)p * KB * npp + dl;
    int s = 0;
    for (int b = 0; b < KB; ++b) s += cntarr[base + (size_t)b * npp];
    indeg[d] = s;
}

__global__ void k_scan_local(const int* __restrict__ in, int* __restrict__ out,
                             int* __restrict__ partials, int n) {
    __shared__ int s[256];
    int t = threadIdx.x;
    int base = blockIdx.x * 1024 + t * 4;
    int v0 = (base + 0) < n ? in[base + 0] : 0;
    int v1 = (base + 1) < n ? in[base + 1] : 0;
    int v2 = (base + 2) < n ? in[base + 2] : 0;
    int v3 = (base + 3) < n ? in[base + 3] : 0;
    int sum = v0 + v1 + v2 + v3;
    s[t] = sum;
    __syncthreads();
    for (int off = 1; off < 256; off <<= 1) {
        int x = (t >= off) ? s[t - off] : 0;
        __syncthreads();
        s[t] += x;
        __syncthreads();
    }
    int excl = s[t] - sum;
    if ((base + 0) < n) out[base + 0] = excl;
    if ((base + 1) < n) out[base + 1] = excl + v0;
    if ((base + 2) < n) out[base + 2] = excl + v0 + v1;
    if ((base + 3) < n) out[base + 3] = excl + v0 + v1 + v2;
    if (t == 255) partials[blockIdx.x] = s[255];
}

__global__ void k_scan_partials(int* __restrict__ partials, int np) {
    __shared__ int s[256];
    int t = threadIdx.x;
    int v = (t < np) ? partials[t] : 0;
    s[t] = v;
    __syncthreads();
    for (int off = 1; off < 256; off <<= 1) {
        int x = (t >= off) ? s[t - off] : 0;
        __syncthreads();
        s[t] += x;
        __syncthreads();
    }
    if (t < np) partials[t] = s[t] - v;
}

__global__ void k_finalize(int* __restrict__ row_ptr, const int* __restrict__ partials,
                           const int* __restrict__ indeg, float* __restrict__ dinv,
                           int n, int E) {
    int i = blockIdx.x * blockDim.x + threadIdx.x;
    if (i < n) {
        int rp = row_ptr[i] + partials[i >> 10];
        row_ptr[i] = rp;
        dinv[i] = rsqrtf((float)indeg[i] + 1.0f);  // +1 = self loop
        if (i == 0) row_ptr[n] = E;
    }
}

__global__ void k_bases(int* __restrict__ cntarr, const int* __restrict__ row_ptr,
                        int n, int npp) {
    int d = blockIdx.x * blockDim.x + threadIdx.x;
    if (d >= n) return;
    int p = (unsigned)d / (unsigned)npp;
    int dl = d - p * npp;
    size_t base = (size_t)p * KB * npp + dl;
    int run = row_ptr[d];
    for (int b = 0; b < KB; ++b) {
        size_t idx = base + (size_t)b * npp;
        int c = cntarr[idx];
        cntarr[idx] = run;
        run += c;
    }
}

__global__ __launch_bounds__(256) void k_fill2(const int2* __restrict__ pairs,
                                               const int* __restrict__ bucketBase,
                                               const int* __restrict__ bucketCount,
                                               const int* __restrict__ cntarr,
                                               int* __restrict__ col, int npp) {
    __shared__ int cur[NPP_MAX];
    int p = blockIdx.x & (NPART - 1);
    int b = blockIdx.x >> 3;
    int lo = p * npp;
    size_t slice = (size_t)(p * KB + b) * npp;
    for (int i = threadIdx.x; i < npp; i += 256) cur[i] = cntarr[slice + i];
    __syncthreads();
    int segBase = bucketBase[p], sz = bucketCount[p];
    int chunk = (sz + KB - 1) / KB;
    int s0 = segBase + b * chunk;
    int s1 = min(segBase + sz, s0 + chunk);
    for (int i = s0 + threadIdx.x; i < s1; i += 256) {
        int2 e = pairs[i];
        int pos = atomicAdd(&cur[e.x - lo], 1);
        col[pos] = e.y;
    }
}

// ---------------- MFMA GEMMs ----------------
// mfma_f32_16x16x32_bf16 layouts (HW-verified per guide §3):
//   A[m = lane&15][k = (lane>>4)*8 + j]   (8 bf16 / lane)
//   B[k = (lane>>4)*8 + j][n = lane&15]
//   C/D: col = lane&15, row = (lane>>4)*4 + reg
typedef __attribute__((ext_vector_type(8))) short short8;
typedef __attribute__((ext_vector_type(4))) float f32x4;

union FragU {
    short8 s;
    uint4 u4;
    unsigned u[4];
};

// Pack W[K x NOUT] fp32 row-major into B-fragment stream:
// Bp[((q*NT + nt)*64 + lane)] = 8 bf16, element j = W[q*32+(lane>>4)*8+j][nt*16+(lane&15)]
template <int NOUT>
__global__ void k_packW(const float* __restrict__ W, unsigned* __restrict__ Bp) {
    const int NT = NOUT / 16;
    int nf = 4 * NT * 64;
    for (int fid = threadIdx.x; fid < nf; fid += 256) {
        int q = fid / (NT * 64);
        int rem = fid - q * NT * 64;
        int nt = rem >> 6;
        int lane = rem & 63;
        int k0 = q * 32 + (lane >> 4) * 8;
        int ncol = nt * 16 + (lane & 15);
        unsigned u[4];
        for (int h = 0; h < 4; ++h) {
            float a = W[(k0 + 2 * h) * NOUT + ncol];
            float b = W[(k0 + 2 * h + 1) * NOUT + ncol];
            u[h] = pack_bf16x2(a, b);
        }
        uint4 o = {u[0], u[1], u[2], u[3]};
        *(uint4*)(Bp + (size_t)fid * 4) = o;
    }
}

// H1f8[N x 128 fp8] = fp8( dinv[row] * (X @ W1) ). X fp32 row-major.
// Block: 64 rows (4 waves x 16), full 128 cols. No LDS: direct A loads.
__global__ __launch_bounds__(256) void k_gemm128_mfma(const float* __restrict__ X,
                                                      const unsigned* __restrict__ Bp,
                                                      const float* __restrict__ dinv,
                                                      unsigned char* __restrict__ H8,
                                                      int n) {
    int w = threadIdx.x >> 6;
    int lane = threadIdx.x & 63;
    int quad = lane >> 4;
    int lrow = lane & 15;
    int row0 = blockIdx.x * 64 + w * 16;
    int rowA = min(row0 + lrow, n - 1);

    f32x4 acc[8];
    for (int nt = 0; nt < 8; ++nt) acc[nt] = (f32x4){0.f, 0.f, 0.f, 0.f};

    for (int q = 0; q < 4; ++q) {
        // A fragment: X[rowA][q*32 + quad*8 .. +8] -> bf16x8
        const float* xp = X + (size_t)rowA * 128 + q * 32 + quad * 8;
        float4 x0 = *(const float4*)xp;
        float4 x1 = *(const float4*)(xp + 4);
        FragU a;
        a.u[0] = pack_bf16x2(x0.x, x0.y);
        a.u[1] = pack_bf16x2(x0.z, x0.w);
        a.u[2] = pack_bf16x2(x1.x, x1.y);
        a.u[3] = pack_bf16x2(x1.z, x1.w);
        for (int nt = 0; nt < 8; ++nt) {
            FragU b;
            b.u4 = *(const uint4*)(Bp + ((size_t)(q * 8 + nt) * 64 + lane) * 4);
            acc[nt] = __builtin_amdgcn_mfma_f32_16x16x32_bf16(a.s, b.s, acc[nt], 0, 0, 0);
        }
    }

    // dinv for this lane's 4 rows (consecutive: quad*4 + r)
    int rbase = row0 + quad * 4;
    float dv[4];
    if (rbase + 3 < n) {
        float4 d4 = *(const float4*)(dinv + rbase);
        dv[0] = d4.x; dv[1] = d4.y; dv[2] = d4.z; dv[3] = d4.w;
    } else {
        for (int r = 0; r < 4; ++r) dv[r] = dinv[min(rbase + r, n - 1)];
    }
    for (int nt = 0; nt < 8; ++nt) {
        for (int r = 0; r < 4; ++r) {
            int row = rbase + r;
            if (row < n)
                H8[(size_t)row * 128 + nt * 16 + lrow] = f32_to_fp8_b(dv[r] * acc[nt][r]);
        }
    }
}

// H2b[N x 64 bf16] = bf16( dinv[row] * (A1 @ W2) ). A1 = packed bf16 (64 uints/row).
__global__ __launch_bounds__(256) void k_gemm64_mfma(const unsigned* __restrict__ Xb,
                                                     const unsigned* __restrict__ Bp,
                                                     const float* __restrict__ dinv,
                                                     unsigned short* __restrict__ H16,
                                                     int n) {
    int w = threadIdx.x >> 6;
    int lane = threadIdx.x & 63;
    int quad = lane >> 4;
    int lrow = lane & 15;
    int row0 = blockIdx.x * 64 + w * 16;
    int rowA = min(row0 + lrow, n - 1);

    f32x4 acc[4];
    for (int nt = 0; nt < 4; ++nt) acc[nt] = (f32x4){0.f, 0.f, 0.f, 0.f};

    for (int q = 0; q < 4; ++q) {
        FragU a;
        a.u4 = *(const uint4*)(Xb + (size_t)rowA * 64 + q * 16 + quad * 4);
        for (int nt = 0; nt < 4; ++nt) {
            FragU b;
            b.u4 = *(const uint4*)(Bp + ((size_t)(q * 4 + nt) * 64 + lane) * 4);
            acc[nt] = __builtin_amdgcn_mfma_f32_16x16x32_bf16(a.s, b.s, acc[nt], 0, 0, 0);
        }
    }

    int rbase = row0 + quad * 4;
    float dv[4];
    if (rbase + 3 < n) {
        float4 d4 = *(const float4*)(dinv + rbase);
        dv[0] = d4.x; dv[1] = d4.y; dv[2] = d4.z; dv[3] = d4.w;
    } else {
        for (int r = 0; r < 4; ++r) dv[r] = dinv[min(rbase + r, n - 1)];
    }
    for (int nt = 0; nt < 4; ++nt) {
        for (int r = 0; r < 4; ++r) {
            int row = rbase + r;
            if (row < n)
                H16[(size_t)row * 64 + nt * 16 + lrow] = bf16_rne(dv[r] * acc[nt][r]);
        }
    }
}

// ---------------- Pull-mode aggregation: half-wave per neighbor ----------------

// Layer 1: hs rows = 32 uints (128 fp8). Lane owns cols 4l..4l+3.
__global__ __launch_bounds__(256) void k_agg_relu(const unsigned* __restrict__ hs,
                                                  const float* __restrict__ dinv,
                                                  const int* __restrict__ row_ptr,
                                                  const int* __restrict__ col,
                                                  const float* __restrict__ bias,
                                                  unsigned* __restrict__ out, int n) {
    int node = blockIdx.x * 4 + (threadIdx.x >> 6);
    if (node >= n) return;
    int lane = threadIdx.x & 63;
    int half = lane >> 5;
    int l = lane & 31;
    float a0 = 0.f, a1 = 0.f, a2 = 0.f, a3 = 0.f;
    if (half == 0) {
        unsigned u = hs[(size_t)node * 32 + l];
        float2 f01 = fp8x2_to_f32_sel<false>(u);
        float2 f23 = fp8x2_to_f32_sel<true>(u);
        a0 = f01.x; a1 = f01.y; a2 = f23.x; a3 = f23.y;
    }
    int p0 = row_ptr[node], p1 = row_ptr[node + 1];
    for (int base = p0; base < p1; base += 64) {
        int nb = min(64, p1 - base);
        int myc = col[base + min(lane, nb - 1)];
        int k = 0;
        for (; k + 8 <= nb; k += 8) {
            int jA = __shfl(myc, k + half);
            int jB = __shfl(myc, k + 2 + half);
            int jC = __shfl(myc, k + 4 + half);
            int jD = __shfl(myc, k + 6 + half);
            unsigned uA = hs[(size_t)jA * 32 + l];
            unsigned uB = hs[(size_t)jB * 32 + l];
            unsigned uC = hs[(size_t)jC * 32 + l];
            unsigned uD = hs[(size_t)jD * 32 + l];
            float2 fA0 = fp8x2_to_f32_sel<false>(uA), fA1 = fp8x2_to_f32_sel<true>(uA);
            float2 fB0 = fp8x2_to_f32_sel<false>(uB), fB1 = fp8x2_to_f32_sel<true>(uB);
            float2 fC0 = fp8x2_to_f32_sel<false>(uC), fC1 = fp8x2_to_f32_sel<true>(uC);
            float2 fD0 = fp8x2_to_f32_sel<false>(uD), fD1 = fp8x2_to_f32_sel<true>(uD);
            a0 += (fA0.x + fB0.x) + (fC0.x + fD0.x);
            a1 += (fA0.y + fB0.y) + (fC0.y + fD0.y);
            a2 += (fA1.x + fB1.x) + (fC1.x + fD1.x);
            a3 += (fA1.y + fB1.y) + (fC1.y + fD1.y);
        }
        for (; k < nb; k += 2) {
            int kk = k + half;
            if (kk < nb) {
                int j = __shfl(myc, kk);
                unsigned u = hs[(size_t)j * 32 + l];
                float2 f0 = fp8x2_to_f32_sel<false>(u);
                float2 f1 = fp8x2_to_f32_sel<true>(u);
                a0 += f0.x; a1 += f0.y; a2 += f1.x; a3 += f1.y;
            }
        }
    }
    a0 += __shfl_xor(a0, 32);
    a1 += __shfl_xor(a1, 32);
    a2 += __shfl_xor(a2, 32);
    a3 += __shfl_xor(a3, 32);
    float di = dinv[node];
    if (half == 0) {
        float4 b4 = *(const float4*)(bias + 4 * l);
        a0 = fmaf(di, a0, b4.x);
        a1 = fmaf(di, a1, b4.y);
        a2 = fmaf(di, a2, b4.z);
        a3 = fmaf(di, a3, b4.w);
        a0 = a0 > 0.f ? a0 : 0.f;
        a1 = a1 > 0.f ? a1 : 0.f;
        a2 = a2 > 0.f ? a2 : 0.f;
        a3 = a3 > 0.f ? a3 : 0.f;
        uint2 o = {pack_bf16x2(a0, a1), pack_bf16x2(a2, a3)};
        *(uint2*)(out + (size_t)node * 64 + 2 * l) = o;
    }
}

// Layer 2: hs rows = 32 uints (64 bf16). Lane owns cols 2l, 2l+1.
__global__ __launch_bounds__(256) void k_agg_lsm(const unsigned* __restrict__ hs,
                                                 const float* __restrict__ dinv,
                                                 const int* __restrict__ row_ptr,
                                                 const int* __restrict__ col,
                                                 const float* __restrict__ bias,
                                                 float* __restrict__ out, int n) {
    int node = blockIdx.x * 4 + (threadIdx.x >> 6);
    if (node >= n) return;
    int lane = threadIdx.x & 63;
    int half = lane >> 5;
    int l = lane & 31;
    float ax = 0.f, ay = 0.f;
    if (half == 0) {
        unsigned u = hs[(size_t)node * 32 + l];
        ax = bf16lo(u);
        ay = bf16hi(u);
    }
    int p0 = row_ptr[node], p1 = row_ptr[node + 1];
    for (int base = p0; base < p1; base += 64) {
        int nb = min(64, p1 - base);
        int myc = col[base + min(lane, nb - 1)];
        int k = 0;
        for (; k + 8 <= nb; k += 8) {
            int jA = __shfl(myc, k + half);
            int jB = __shfl(myc, k + 2 + half);
            int jC = __shfl(myc, k + 4 + half);
            int jD = __shfl(myc, k + 6 + half);
            unsigned uA = hs[(size_t)jA * 32 + l];
            unsigned uB = hs[(size_t)jB * 32 + l];
            unsigned uC = hs[(size_t)jC * 32 + l];
            unsigned uD = hs[(size_t)jD * 32 + l];
            ax += (bf16lo(uA) + bf16lo(uB)) + (bf16lo(uC) + bf16lo(uD));
            ay += (bf16hi(uA) + bf16hi(uB)) + (bf16hi(uC) + bf16hi(uD));
        }
        for (; k < nb; k += 2) {
            int kk = k + half;
            if (kk < nb) {
                int j = __shfl(myc, kk);
                unsigned u = hs[(size_t)j * 32 + l];
                ax += bf16lo(u);
                ay += bf16hi(u);
            }
        }
    }
    ax += __shfl_xor(ax, 32);
    ay += __shfl_xor(ay, 32);
    float di = dinv[node];
    float2 b2 = ((const float2*)bias)[l];
    float vx = fmaf(di, ax, b2.x);
    float vy = fmaf(di, ay, b2.y);
    float m = fmaxf(vx, vy);
    for (int off = 16; off; off >>= 1) m = fmaxf(m, __shfl_xor(m, off));
    float s = __expf(vx - m) + __expf(vy - m);
    for (int off = 16; off; off >>= 1) s += __shfl_xor(s, off);
    float ls = __logf(s);
    if (half == 0) {
        float2 o = {vx - m - ls, vy - m - ls};
        ((float2*)(out + (size_t)node * 64))[l] = o;
    }
}

// ---------------- launcher ----------------

extern "C" void kernel_launch(void* const* d_in, const int* in_sizes, int n_in,
                              void* d_out, int out_size, void* d_ws, size_t ws_size,
                              hipStream_t stream) {
    const float* x  = (const float*)d_in[0];
    const int*   ei = (const int*)d_in[1];
    const float* W1 = (const float*)d_in[2];
    const float* b1 = (const float*)d_in[3];
    const float* W2 = (const float*)d_in[4];
    const float* b2 = (const float*)d_in[5];
    float* out = (float*)d_out;

    const int N = in_sizes[0] / 128;   // 100000
    const int E = in_sizes[1] / 2;     // 1600000
    const int* src = ei;
    const int* dst = ei + E;
    const int npp = (N + NPART - 1) / NPART;  // 12500

    char* w = (char*)d_ws;
    size_t off = 0;
    auto alloc = [&](size_t bytes) -> void* {
        void* p = w + off;
        off += (bytes + 255) & ~(size_t)255;
        return p;
    };
    int*      indeg    = (int*)alloc((size_t)N * 4);
    int*      row_ptr  = (int*)alloc((size_t)(N + 1) * 4);
    int*      colarr   = (int*)alloc((size_t)E * 4);
    int*      partials = (int*)alloc(256 * 4);
    int*      bmeta    = (int*)alloc(16 * 4);
    int*      bbase    = (int*)alloc(NPART * 4);
    float*    dinv     = (float*)alloc((size_t)N * 4);
    unsigned* h1f8     = (unsigned*)alloc((size_t)N * 32 * 4);  // fp8 X@W1 scaled
    unsigned* a1b      = (unsigned*)alloc((size_t)N * 64 * 4);  // bf16 relu out
    unsigned* h2b      = (unsigned*)alloc((size_t)N * 32 * 4);  // bf16 a1@W2 scaled
    unsigned* Bp1      = (unsigned*)alloc(4 * 8 * 64 * 16);     // W1 frag stream 32KB
    unsigned* Bp2      = (unsigned*)alloc(4 * 4 * 64 * 16);     // W2 frag stream 16KB
    int2* pairs  = (int2*)a1b;
    int*  cntarr = (int*)((char*)a1b + (size_t)E * 8);
    (void)ws_size; (void)n_in; (void)out_size;

    int* bucketCount  = bmeta;
    int* bucketCursor = bmeta + 8;
    int nscan = (N + 1023) / 1024;
    int nA3 = (E + 4095) / 4096;
    int ngemm = (N + 63) / 64;

    k_zero16<<<1, 64, 0, stream>>>(bmeta);
    k_packW<128><<<1, 256, 0, stream>>>(W1, Bp1);
    k_packW<64><<<1, 256, 0, stream>>>(W2, Bp2);
    k_bcount<<<256, 256, 0, stream>>>(dst, bucketCount, E, npp);
    k_bscan<<<1, 64, 0, stream>>>(bucketCount, bbase, bucketCursor);
    k_bucket<<<nA3, 256, 0, stream>>>(src, dst, bucketCursor, pairs, E, npp);
    k_count_part<<<NPART * KB, 256, 0, stream>>>(pairs, bbase, bucketCount, cntarr, npp);
    k_indeg<<<(N + 255) / 256, 256, 0, stream>>>(cntarr, indeg, N, npp);
    k_scan_local<<<nscan, 256, 0, stream>>>(indeg, row_ptr, partials, N);
    k_scan_partials<<<1, 256, 0, stream>>>(partials, nscan);
    k_finalize<<<(N + 255) / 256, 256, 0, stream>>>(row_ptr, partials, indeg, dinv, N, E);
    k_bases<<<(N + 255) / 256, 256, 0, stream>>>(cntarr, row_ptr, N, npp);
    k_fill2<<<NPART * KB, 256, 0, stream>>>(pairs, bbase, bucketCount, cntarr,
                                            colarr, npp);

    k_gemm128_mfma<<<ngemm, 256, 0, stream>>>(x, Bp1, dinv, (unsigned char*)h1f8, N);
    k_agg_relu<<<(N + 3) / 4, 256, 0, stream>>>(h1f8, dinv, row_ptr, colarr, b1, a1b, N);
    k_gemm64_mfma<<<ngemm, 256, 0, stream>>>(a1b, Bp2, dinv, (unsigned short*)h2b, N);
    k_agg_lsm<<<(N + 3) / 4, 256, 0, stream>>>(h2b, dinv, row_ptr, colarr, b2, out, N);
}

// Round 15
// 302.314 us; speedup vs baseline: 1.2199x; 1.0149x over previous
//
#include <hip/hip_runtime.h>
#include <hip/hip_fp16.h>
#include <cstdint>
#include <cstddef>
#include <cstring>

// ---------------- bf16 pack/unpack helpers (RNE) ----------------

__device__ inline unsigned pack_bf16x2(float a, float b) {
    unsigned ua = __float_as_uint(a);
    unsigned ub = __float_as_uint(b);
    ua += 0x7fffu + ((ua >> 16) & 1u);
    ub += 0x7fffu + ((ub >> 16) & 1u);
    return (ua >> 16) | (ub & 0xffff0000u);
}
__device__ inline unsigned short bf16_rne(float v) {
    unsigned u = __float_as_uint(v);
    u += 0x7fffu + ((u >> 16) & 1u);
    return (unsigned short)(u >> 16);
}
__device__ inline float bf16lo(unsigned u) { return __uint_as_float(u << 16); }
__device__ inline float bf16hi(unsigned u) { return __uint_as_float(u & 0xffff0000u); }

// ---------------- fp8 (OCP e4m3fn) pack/unpack ----------------

typedef float fv2 __attribute__((ext_vector_type(2)));

template <bool HI>
__device__ inline float2 fp8x2_to_f32_sel(unsigned u) {
#if __has_builtin(__builtin_amdgcn_cvt_pk_f32_fp8)
    fv2 r = __builtin_amdgcn_cvt_pk_f32_fp8((int)u, HI);
    return make_float2(r.x, r.y);
#else
    unsigned u2 = HI ? (u >> 16) : (u & 0xffffu);
    unsigned w = (u2 & 0xFFu) | ((u2 & 0xFF00u) << 8);
    unsigned hb = ((w & 0x00800080u) << 8) | ((w & 0x007f007fu) << 7);
    __half2 h2;
    memcpy(&h2, &hb, 4);
    float2 f = __half22float2(h2);
    f.x *= 256.0f;
    f.y *= 256.0f;
    return f;
#endif
}

__device__ inline unsigned f32_to_fp8_byte(float v) {
    unsigned short hb = __half_as_ushort(__float2half(v * 0.00390625f));  // v/256
    unsigned t = hb & 0x7fffu;
    t += 0x3fu + ((t >> 7) & 1u);
    return ((hb >> 8) & 0x80u) | (t >> 7);
}

__device__ inline unsigned char f32_to_fp8_b(float v) {
#if __has_builtin(__builtin_amdgcn_cvt_pk_fp8_f32)
    return (unsigned char)(__builtin_amdgcn_cvt_pk_fp8_f32(v, v, 0, false) & 0xff);
#else
    return (unsigned char)f32_to_fp8_byte(v);
#endif
}

typedef int iv4 __attribute__((ext_vector_type(4)));

#define NPART 8
#define KB    32
#define NPP_MAX 12500

// ---------------- CSR build: atomic-free counting-sort pipeline ----------------

__global__ void k_zero16(int* __restrict__ p) {
    if (threadIdx.x < 16) p[threadIdx.x] = 0;
}

__global__ __launch_bounds__(256) void k_bcount(const int* __restrict__ dst,
                                                int* __restrict__ bucketCount,
                                                int E, int npp) {
    __shared__ int c8[NPART];
    if (threadIdx.x < NPART) c8[threadIdx.x] = 0;
    __syncthreads();
    int t = blockIdx.x * blockDim.x + threadIdx.x;
    int stride = gridDim.x * blockDim.x;
    int E4 = E >> 2;
    const iv4* d4 = (const iv4*)dst;
    for (int i = t; i < E4; i += stride) {
        iv4 d = d4[i];
        atomicAdd(&c8[(unsigned)d.x / (unsigned)npp], 1);
        atomicAdd(&c8[(unsigned)d.y / (unsigned)npp], 1);
        atomicAdd(&c8[(unsigned)d.z / (unsigned)npp], 1);
        atomicAdd(&c8[(unsigned)d.w / (unsigned)npp], 1);
    }
    for (int e = E4 * 4 + t; e < E; e += stride)
        atomicAdd(&c8[(unsigned)dst[e] / (unsigned)npp], 1);
    __syncthreads();
    if (threadIdx.x < NPART) atomicAdd(&bucketCount[threadIdx.x], c8[threadIdx.x]);
}

__global__ void k_bscan(const int* __restrict__ bucketCount,
                        int* __restrict__ bucketBase,
                        int* __restrict__ bucketCursor) {
    if (threadIdx.x == 0) {
        int run = 0;
        for (int p = 0; p < NPART; ++p) {
            bucketBase[p] = run;
            bucketCursor[p] = run;
            run += bucketCount[p];
        }
    }
}

__global__ __launch_bounds__(256) void k_bucket(const int* __restrict__ src,
                                                const int* __restrict__ dst,
                                                int* __restrict__ bucketCursor,
                                                int2* __restrict__ pairs,
                                                int E, int npp) {
    __shared__ int cnt8[NPART], run8[NPART], gbase8[NPART];
    int tid = threadIdx.x;
    int base_e = blockIdx.x * 4096 + tid * 16;
    int nv = min(16, E - base_e);
    if (nv < 0) nv = 0;
    int dv[16], sv[16];
    if (nv == 16) {
        for (int q = 0; q < 4; ++q) {
            iv4 d = *(const iv4*)(dst + base_e + q * 4);
            iv4 s = *(const iv4*)(src + base_e + q * 4);
            dv[q * 4 + 0] = d.x; dv[q * 4 + 1] = d.y; dv[q * 4 + 2] = d.z; dv[q * 4 + 3] = d.w;
            sv[q * 4 + 0] = s.x; sv[q * 4 + 1] = s.y; sv[q * 4 + 2] = s.z; sv[q * 4 + 3] = s.w;
        }
    } else {
        for (int k = 0; k < nv; ++k) { dv[k] = dst[base_e + k]; sv[k] = src[base_e + k]; }
    }
    if (tid < NPART) { cnt8[tid] = 0; run8[tid] = 0; }
    __syncthreads();
    for (int k = 0; k < nv; ++k)
        atomicAdd(&cnt8[(unsigned)dv[k] / (unsigned)npp], 1);
    __syncthreads();
    if (tid < NPART) gbase8[tid] = atomicAdd(&bucketCursor[tid], cnt8[tid]);
    __syncthreads();
    for (int k = 0; k < nv; ++k) {
        int p = (unsigned)dv[k] / (unsigned)npp;
        int r = atomicAdd(&run8[p], 1);
        int2 pr; pr.x = dv[k]; pr.y = sv[k];
        pairs[gbase8[p] + r] = pr;
    }
}

__global__ __launch_bounds__(256) void k_count_part(const int2* __restrict__ pairs,
                                                    const int* __restrict__ bucketBase,
                                                    const int* __restrict__ bucketCount,
                                                    int* __restrict__ cntarr, int npp) {
    __shared__ int h[NPP_MAX];
    int p = blockIdx.x & (NPART - 1);
    int b = blockIdx.x >> 3;
    int lo = p * npp;
    for (int i = threadIdx.x; i < npp; i += 256) h[i] = 0;
    __syncthreads();
    int segBase = bucketBase[p], sz = bucketCount[p];
    int chunk = (sz + KB - 1) / KB;
    int s0 = segBase + b * chunk;
    int s1 = min(segBase + sz, s0 + chunk);
    for (int i = s0 + threadIdx.x; i < s1; i += 256)
        atomicAdd(&h[pairs[i].x - lo], 1);
    __syncthreads();
    size_t out = (size_t)(p * KB + b) * npp;
    for (int i = threadIdx.x; i < npp; i += 256) cntarr[out + i] = h[i];
}

__global__ void k_indeg(const int* __restrict__ cntarr, int* __restrict__ indeg,
                        int n, int npp) {
    int d = blockIdx.x * blockDim.x + threadIdx.x;
    if (d >= n) return;
    int p = (unsigned)d / (unsigned)npp;
    int dl = d - p * npp;
    size_t base = (size_t)p * KB * npp + dl;
    int s = 0;
    for (int b = 0; b < KB; ++b) s += cntarr[base + (size_t)b * npp];
    indeg[d] = s;
}

__global__ void k_scan_local(const int* __restrict__ in, int* __restrict__ out,
                             int* __restrict__ partials, int n) {
    __shared__ int s[256];
    int t = threadIdx.x;
    int base = blockIdx.x * 1024 + t * 4;
    int v0 = (base + 0) < n ? in[base + 0] : 0;
    int v1 = (base + 1) < n ? in[base + 1] : 0;
    int v2 = (base + 2) < n ? in[base + 2] : 0;
    int v3 = (base + 3) < n ? in[base + 3] : 0;
    int sum = v0 + v1 + v2 + v3;
    s[t] = sum;
    __syncthreads();
    for (int off = 1; off < 256; off <<= 1) {
        int x = (t >= off) ? s[t - off] : 0;
        __syncthreads();
        s[t] += x;
        __syncthreads();
    }
    int excl = s[t] - sum;
    if ((base + 0) < n) out[base + 0] = excl;
    if ((base + 1) < n) out[base + 1] = excl + v0;
    if ((base + 2) < n) out[base + 2] = excl + v0 + v1;
    if ((base + 3) < n) out[base + 3] = excl + v0 + v1 + v2;
    if (t == 255) partials[blockIdx.x] = s[255];
}

__global__ void k_scan_partials(int* __restrict__ partials, int np) {
    __shared__ int s[256];
    int t = threadIdx.x;
    int v = (t < np) ? partials[t] : 0;
    s[t] = v;
    __syncthreads();
    for (int off = 1; off < 256; off <<= 1) {
        int x = (t >= off) ? s[t - off] : 0;
        __syncthreads();
        s[t] += x;
        __syncthreads();
    }
    if (t < np) partials[t] = s[t] - v;
}

__global__ void k_finalize(int* __restrict__ row_ptr, const int* __restrict__ partials,
                           const int* __restrict__ indeg, float* __restrict__ dinv,
                           int n, int E) {
    int i = blockIdx.x * blockDim.x + threadIdx.x;
    if (i < n) {
        int rp = row_ptr[i] + partials[i >> 10];
        row_ptr[i] = rp;
        dinv[i] = rsqrtf((float)indeg[i] + 1.0f);  // +1 = self loop
        if (i == 0) row_ptr[n] = E;
    }
}

__global__ void k_bases(int* __restrict__ cntarr, const int* __restrict__ row_ptr,
                        int n, int npp) {
    int d = blockIdx.x * blockDim.x + threadIdx.x;
    if (d >= n) return;
    int p = (unsigned)d / (unsigned)npp;
    int dl = d - p * npp;
    size_t base = (size_t)p * KB * npp + dl;
    int run = row_ptr[d];
    for (int b = 0; b < KB; ++b) {
        size_t idx = base + (size_t)b * npp;
        int c = cntarr[idx];
        cntarr[idx] = run;
        run += c;
    }
}

__global__ __launch_bounds__(256) void k_fill2(const int2* __restrict__ pairs,
                                               const int* __restrict__ bucketBase,
                                               const int* __restrict__ bucketCount,
                                               const int* __restrict__ cntarr,
                                               int* __restrict__ col, int npp) {
    __shared__ int cur[NPP_MAX];
    int p = blockIdx.x & (NPART - 1);
    int b = blockIdx.x >> 3;
    int lo = p * npp;
    size_t slice = (size_t)(p * KB + b) * npp;
    for (int i = threadIdx.x; i < npp; i += 256) cur[i] = cntarr[slice + i];
    __syncthreads();
    int segBase = bucketBase[p], sz = bucketCount[p];
    int chunk = (sz + KB - 1) / KB;
    int s0 = segBase + b * chunk;
    int s1 = min(segBase + sz, s0 + chunk);
    for (int i = s0 + threadIdx.x; i < s1; i += 256) {
        int2 e = pairs[i];
        int pos = atomicAdd(&cur[e.x - lo], 1);
        col[pos] = e.y;
    }
}

// ---------------- MFMA GEMMs ----------------
typedef __attribute__((ext_vector_type(8))) short short8;
typedef __attribute__((ext_vector_type(4))) float f32x4;

union FragU {
    short8 s;
    uint4 u4;
    unsigned u[4];
};

template <int NOUT>
__global__ void k_packW(const float* __restrict__ W, unsigned* __restrict__ Bp) {
    const int NT = NOUT / 16;
    int nf = 4 * NT * 64;
    for (int fid = threadIdx.x; fid < nf; fid += 256) {
        int q = fid / (NT * 64);
        int rem = fid - q * NT * 64;
        int nt = rem >> 6;
        int lane = rem & 63;
        int k0 = q * 32 + (lane >> 4) * 8;
        int ncol = nt * 16 + (lane & 15);
        unsigned u[4];
        for (int h = 0; h < 4; ++h) {
            float a = W[(k0 + 2 * h) * NOUT + ncol];
            float b = W[(k0 + 2 * h + 1) * NOUT + ncol];
            u[h] = pack_bf16x2(a, b);
        }
        uint4 o = {u[0], u[1], u[2], u[3]};
        *(uint4*)(Bp + (size_t)fid * 4) = o;
    }
}

__global__ __launch_bounds__(256) void k_gemm128_mfma(const float* __restrict__ X,
                                                      const unsigned* __restrict__ Bp,
                                                      const float* __restrict__ dinv,
                                                      unsigned char* __restrict__ H8,
                                                      int n) {
    int w = threadIdx.x >> 6;
    int lane = threadIdx.x & 63;
    int quad = lane >> 4;
    int lrow = lane & 15;
    int row0 = blockIdx.x * 64 + w * 16;
    int rowA = min(row0 + lrow, n - 1);

    f32x4 acc[8];
    for (int nt = 0; nt < 8; ++nt) acc[nt] = (f32x4){0.f, 0.f, 0.f, 0.f};

    for (int q = 0; q < 4; ++q) {
        const float* xp = X + (size_t)rowA * 128 + q * 32 + quad * 8;
        float4 x0 = *(const float4*)xp;
        float4 x1 = *(const float4*)(xp + 4);
        FragU a;
        a.u[0] = pack_bf16x2(x0.x, x0.y);
        a.u[1] = pack_bf16x2(x0.z, x0.w);
        a.u[2] = pack_bf16x2(x1.x, x1.y);
        a.u[3] = pack_bf16x2(x1.z, x1.w);
        for (int nt = 0; nt < 8; ++nt) {
            FragU b;
            b.u4 = *(const uint4*)(Bp + ((size_t)(q * 8 + nt) * 64 + lane) * 4);
            acc[nt] = __builtin_amdgcn_mfma_f32_16x16x32_bf16(a.s, b.s, acc[nt], 0, 0, 0);
        }
    }

    int rbase = row0 + quad * 4;
    float dv[4];
    if (rbase + 3 < n) {
        float4 d4 = *(const float4*)(dinv + rbase);
        dv[0] = d4.x; dv[1] = d4.y; dv[2] = d4.z; dv[3] = d4.w;
    } else {
        for (int r = 0; r < 4; ++r) dv[r] = dinv[min(rbase + r, n - 1)];
    }
    for (int nt = 0; nt < 8; ++nt) {
        for (int r = 0; r < 4; ++r) {
            int row = rbase + r;
            if (row < n)
                H8[(size_t)row * 128 + nt * 16 + lrow] = f32_to_fp8_b(dv[r] * acc[nt][r]);
        }
    }
}

__global__ __launch_bounds__(256) void k_gemm64_mfma(const unsigned* __restrict__ Xb,
                                                     const unsigned* __restrict__ Bp,
                                                     const float* __restrict__ dinv,
                                                     unsigned short* __restrict__ H16,
                                                     int n) {
    int w = threadIdx.x >> 6;
    int lane = threadIdx.x & 63;
    int quad = lane >> 4;
    int lrow = lane & 15;
    int row0 = blockIdx.x * 64 + w * 16;
    int rowA = min(row0 + lrow, n - 1);

    f32x4 acc[4];
    for (int nt = 0; nt < 4; ++nt) acc[nt] = (f32x4){0.f, 0.f, 0.f, 0.f};

    for (int q = 0; q < 4; ++q) {
        FragU a;
        a.u4 = *(const uint4*)(Xb + (size_t)rowA * 64 + q * 16 + quad * 4);
        for (int nt = 0; nt < 4; ++nt) {
            FragU b;
            b.u4 = *(const uint4*)(Bp + ((size_t)(q * 4 + nt) * 64 + lane) * 4);
            acc[nt] = __builtin_amdgcn_mfma_f32_16x16x32_bf16(a.s, b.s, acc[nt], 0, 0, 0);
        }
    }

    int rbase = row0 + quad * 4;
    float dv[4];
    if (rbase + 3 < n) {
        float4 d4 = *(const float4*)(dinv + rbase);
        dv[0] = d4.x; dv[1] = d4.y; dv[2] = d4.z; dv[3] = d4.w;
    } else {
        for (int r = 0; r < 4; ++r) dv[r] = dinv[min(rbase + r, n - 1)];
    }
    for (int nt = 0; nt < 4; ++nt) {
        for (int r = 0; r < 4; ++r) {
            int row = rbase + r;
            if (row < n)
                H16[(size_t)row * 64 + nt * 16 + lrow] = bf16_rne(dv[r] * acc[nt][r]);
        }
    }
}

// ---------------- Pull-mode aggregation: half-wave per neighbor ----------------
// R11-proven structure (passed at 0.03125): lanes 0-31 even-k, 32-63 odd-k;
// only the unroll depth is raised 4 -> 8 loads (16 edges/iter, 16 requests
// in flight). Per-edge index/data mapping is IDENTICAL to R11.

// Layer 1: hs rows = 32 uints (128 fp8). Lane owns cols 4l..4l+3.
__global__ __launch_bounds__(256) void k_agg_relu(const unsigned* __restrict__ hs,
                                                  const float* __restrict__ dinv,
                                                  const int* __restrict__ row_ptr,
                                                  const int* __restrict__ col,
                                                  const float* __restrict__ bias,
                                                  unsigned* __restrict__ out, int n) {
    int node = blockIdx.x * 4 + (threadIdx.x >> 6);
    if (node >= n) return;
    int lane = threadIdx.x & 63;
    int half = lane >> 5;
    int l = lane & 31;
    float a0 = 0.f, a1 = 0.f, a2 = 0.f, a3 = 0.f;
    if (half == 0) {  // self term counted once
        unsigned u = hs[(size_t)node * 32 + l];
        float2 f01 = fp8x2_to_f32_sel<false>(u);
        float2 f23 = fp8x2_to_f32_sel<true>(u);
        a0 = f01.x; a1 = f01.y; a2 = f23.x; a3 = f23.y;
    }
    int p0 = row_ptr[node], p1 = row_ptr[node + 1];
    for (int base = p0; base < p1; base += 64) {
        int nb = min(64, p1 - base);
        int myc = col[base + min(lane, nb - 1)];
        int k = 0;
        for (; k + 16 <= nb; k += 16) {  // 16 edges, 8 independent loads
            int jA = __shfl(myc, k + half);
            int jB = __shfl(myc, k + 2 + half);
            int jC = __shfl(myc, k + 4 + half);
            int jD = __shfl(myc, k + 6 + half);
            int jE = __shfl(myc, k + 8 + half);
            int jF = __shfl(myc, k + 10 + half);
            int jG = __shfl(myc, k + 12 + half);
            int jH = __shfl(myc, k + 14 + half);
            unsigned uA = hs[(size_t)jA * 32 + l];
            unsigned uB = hs[(size_t)jB * 32 + l];
            unsigned uC = hs[(size_t)jC * 32 + l];
            unsigned uD = hs[(size_t)jD * 32 + l];
            unsigned uE = hs[(size_t)jE * 32 + l];
            unsigned uF = hs[(size_t)jF * 32 + l];
            unsigned uG = hs[(size_t)jG * 32 + l];
            unsigned uH = hs[(size_t)jH * 32 + l];
            float2 f;
            f = fp8x2_to_f32_sel<false>(uA); a0 += f.x; a1 += f.y;
            f = fp8x2_to_f32_sel<true>(uA);  a2 += f.x; a3 += f.y;
            f = fp8x2_to_f32_sel<false>(uB); a0 += f.x; a1 += f.y;
            f = fp8x2_to_f32_sel<true>(uB);  a2 += f.x; a3 += f.y;
            f = fp8x2_to_f32_sel<false>(uC); a0 += f.x; a1 += f.y;
            f = fp8x2_to_f32_sel<true>(uC);  a2 += f.x; a3 += f.y;
            f = fp8x2_to_f32_sel<false>(uD); a0 += f.x; a1 += f.y;
            f = fp8x2_to_f32_sel<true>(uD);  a2 += f.x; a3 += f.y;
            f = fp8x2_to_f32_sel<false>(uE); a0 += f.x; a1 += f.y;
            f = fp8x2_to_f32_sel<true>(uE);  a2 += f.x; a3 += f.y;
            f = fp8x2_to_f32_sel<false>(uF); a0 += f.x; a1 += f.y;
            f = fp8x2_to_f32_sel<true>(uF);  a2 += f.x; a3 += f.y;
            f = fp8x2_to_f32_sel<false>(uG); a0 += f.x; a1 += f.y;
            f = fp8x2_to_f32_sel<true>(uG);  a2 += f.x; a3 += f.y;
            f = fp8x2_to_f32_sel<false>(uH); a0 += f.x; a1 += f.y;
            f = fp8x2_to_f32_sel<true>(uH);  a2 += f.x; a3 += f.y;
        }
        for (; k + 8 <= nb; k += 8) {  // 8 edges, 4 loads
            int jA = __shfl(myc, k + half);
            int jB = __shfl(myc, k + 2 + half);
            int jC = __shfl(myc, k + 4 + half);
            int jD = __shfl(myc, k + 6 + half);
            unsigned uA = hs[(size_t)jA * 32 + l];
            unsigned uB = hs[(size_t)jB * 32 + l];
            unsigned uC = hs[(size_t)jC * 32 + l];
            unsigned uD = hs[(size_t)jD * 32 + l];
            float2 f;
            f = fp8x2_to_f32_sel<false>(uA); a0 += f.x; a1 += f.y;
            f = fp8x2_to_f32_sel<true>(uA);  a2 += f.x; a3 += f.y;
            f = fp8x2_to_f32_sel<false>(uB); a0 += f.x; a1 += f.y;
            f = fp8x2_to_f32_sel<true>(uB);  a2 += f.x; a3 += f.y;
            f = fp8x2_to_f32_sel<false>(uC); a0 += f.x; a1 += f.y;
            f = fp8x2_to_f32_sel<true>(uC);  a2 += f.x; a3 += f.y;
            f = fp8x2_to_f32_sel<false>(uD); a0 += f.x; a1 += f.y;
            f = fp8x2_to_f32_sel<true>(uD);  a2 += f.x; a3 += f.y;
        }
        for (; k < nb; k += 2) {
            int kk = k + half;
            if (kk < nb) {
                int j = __shfl(myc, kk);
                unsigned u = hs[(size_t)j * 32 + l];
                float2 f0 = fp8x2_to_f32_sel<false>(u);
                float2 f1 = fp8x2_to_f32_sel<true>(u);
                a0 += f0.x; a1 += f0.y; a2 += f1.x; a3 += f1.y;
            }
        }
    }
    a0 += __shfl_xor(a0, 32);
    a1 += __shfl_xor(a1, 32);
    a2 += __shfl_xor(a2, 32);
    a3 += __shfl_xor(a3, 32);
    float di = dinv[node];
    if (half == 0) {
        float4 b4 = *(const float4*)(bias + 4 * l);
        a0 = fmaf(di, a0, b4.x);
        a1 = fmaf(di, a1, b4.y);
        a2 = fmaf(di, a2, b4.z);
        a3 = fmaf(di, a3, b4.w);
        a0 = a0 > 0.f ? a0 : 0.f;
        a1 = a1 > 0.f ? a1 : 0.f;
        a2 = a2 > 0.f ? a2 : 0.f;
        a3 = a3 > 0.f ? a3 : 0.f;
        uint2 o = {pack_bf16x2(a0, a1), pack_bf16x2(a2, a3)};
        *(uint2*)(out + (size_t)node * 64 + 2 * l) = o;
    }
}

// Layer 2: hs rows = 32 uints (64 bf16). Lane owns cols 2l, 2l+1. Fused log_softmax.
__global__ __launch_bounds__(256) void k_agg_lsm(const unsigned* __restrict__ hs,
                                                 const float* __restrict__ dinv,
                                                 const int* __restrict__ row_ptr,
                                                 const int* __restrict__ col,
                                                 const float* __restrict__ bias,
                                                 float* __restrict__ out, int n) {
    int node = blockIdx.x * 4 + (threadIdx.x >> 6);
    if (node >= n) return;
    int lane = threadIdx.x & 63;
    int half = lane >> 5;
    int l = lane & 31;
    float ax = 0.f, ay = 0.f;
    if (half == 0) {
        unsigned u = hs[(size_t)node * 32 + l];
        ax = bf16lo(u);
        ay = bf16hi(u);
    }
    int p0 = row_ptr[node], p1 = row_ptr[node + 1];
    for (int base = p0; base < p1; base += 64) {
        int nb = min(64, p1 - base);
        int myc = col[base + min(lane, nb - 1)];
        int k = 0;
        for (; k + 16 <= nb; k += 16) {  // 16 edges, 8 independent loads
            int jA = __shfl(myc, k + half);
            int jB = __shfl(myc, k + 2 + half);
            int jC = __shfl(myc, k + 4 + half);
            int jD = __shfl(myc, k + 6 + half);
            int jE = __shfl(myc, k + 8 + half);
            int jF = __shfl(myc, k + 10 + half);
            int jG = __shfl(myc, k + 12 + half);
            int jH = __shfl(myc, k + 14 + half);
            unsigned uA = hs[(size_t)jA * 32 + l];
            unsigned uB = hs[(size_t)jB * 32 + l];
            unsigned uC = hs[(size_t)jC * 32 + l];
            unsigned uD = hs[(size_t)jD * 32 + l];
            unsigned uE = hs[(size_t)jE * 32 + l];
            unsigned uF = hs[(size_t)jF * 32 + l];
            unsigned uG = hs[(size_t)jG * 32 + l];
            unsigned uH = hs[(size_t)jH * 32 + l];
            ax += (bf16lo(uA) + bf16lo(uB)) + (bf16lo(uC) + bf16lo(uD)) +
                  (bf16lo(uE) + bf16lo(uF)) + (bf16lo(uG) + bf16lo(uH));
            ay += (bf16hi(uA) + bf16hi(uB)) + (bf16hi(uC) + bf16hi(uD)) +
                  (bf16hi(uE) + bf16hi(uF)) + (bf16hi(uG) + bf16hi(uH));
        }
        for (; k + 8 <= nb; k += 8) {
            int jA = __shfl(myc, k + half);
            int jB = __shfl(myc, k + 2 + half);
            int jC = __shfl(myc, k + 4 + half);
            int jD = __shfl(myc, k + 6 + half);
            unsigned uA = hs[(size_t)jA * 32 + l];
            unsigned uB = hs[(size_t)jB * 32 + l];
            unsigned uC = hs[(size_t)jC * 32 + l];
            unsigned uD = hs[(size_t)jD * 32 + l];
            ax += (bf16lo(uA) + bf16lo(uB)) + (bf16lo(uC) + bf16lo(uD));
            ay += (bf16hi(uA) + bf16hi(uB)) + (bf16hi(uC) + bf16hi(uD));
        }
        for (; k < nb; k += 2) {
            int kk = k + half;
            if (kk < nb) {
                int j = __shfl(myc, kk);
                unsigned u = hs[(size_t)j * 32 + l];
                ax += bf16lo(u);
                ay += bf16hi(u);
            }
        }
    }
    ax += __shfl_xor(ax, 32);
    ay += __shfl_xor(ay, 32);
    float di = dinv[node];
    float2 b2 = ((const float2*)bias)[l];
    float vx = fmaf(di, ax, b2.x);
    float vy = fmaf(di, ay, b2.y);
    float m = fmaxf(vx, vy);
    for (int off = 16; off; off >>= 1) m = fmaxf(m, __shfl_xor(m, off));
    float s = __expf(vx - m) + __expf(vy - m);
    for (int off = 16; off; off >>= 1) s += __shfl_xor(s, off);
    float ls = __logf(s);
    if (half == 0) {
        float2 o = {vx - m - ls, vy - m - ls};
        ((float2*)(out + (size_t)node * 64))[l] = o;
    }
}

// ---------------- launcher ----------------

extern "C" void kernel_launch(void* const* d_in, const int* in_sizes, int n_in,
                              void* d_out, int out_size, void* d_ws, size_t ws_size,
                              hipStream_t stream) {
    const float* x  = (const float*)d_in[0];
    const int*   ei = (const int*)d_in[1];
    const float* W1 = (const float*)d_in[2];
    const float* b1 = (const float*)d_in[3];
    const float* W2 = (const float*)d_in[4];
    const float* b2 = (const float*)d_in[5];
    float* out = (float*)d_out;

    const int N = in_sizes[0] / 128;   // 100000
    const int E = in_sizes[1] / 2;     // 1600000
    const int* src = ei;
    const int* dst = ei + E;
    const int npp = (N + NPART - 1) / NPART;  // 12500

    char* w = (char*)d_ws;
    size_t off = 0;
    auto alloc = [&](size_t bytes) -> void* {
        void* p = w + off;
        off += (bytes + 255) & ~(size_t)255;
        return p;
    };
    int*      indeg    = (int*)alloc((size_t)N * 4);
    int*      row_ptr  = (int*)alloc((size_t)(N + 1) * 4);
    int*      colarr   = (int*)alloc((size_t)E * 4);
    int*      partials = (int*)alloc(256 * 4);
    int*      bmeta    = (int*)alloc(16 * 4);
    int*      bbase    = (int*)alloc(NPART * 4);
    float*    dinv     = (float*)alloc((size_t)N * 4);
    unsigned* h1f8     = (unsigned*)alloc((size_t)N * 32 * 4);  // fp8 X@W1 scaled
    unsigned* a1b      = (unsigned*)alloc((size_t)N * 64 * 4);  // bf16 relu out
    unsigned* h2b      = (unsigned*)alloc((size_t)N * 32 * 4);  // bf16 a1@W2 scaled
    unsigned* Bp1      = (unsigned*)alloc(4 * 8 * 64 * 16);     // W1 frag stream 32KB
    unsigned* Bp2      = (unsigned*)alloc(4 * 4 * 64 * 16);     // W2 frag stream 16KB
    int2* pairs  = (int2*)a1b;
    int*  cntarr = (int*)((char*)a1b + (size_t)E * 8);
    (void)ws_size; (void)n_in; (void)out_size;

    int* bucketCount  = bmeta;
    int* bucketCursor = bmeta + 8;
    int nscan = (N + 1023) / 1024;
    int nA3 = (E + 4095) / 4096;
    int ngemm = (N + 63) / 64;

    k_zero16<<<1, 64, 0, stream>>>(bmeta);
    k_packW<128><<<1, 256, 0, stream>>>(W1, Bp1);
    k_packW<64><<<1, 256, 0, stream>>>(W2, Bp2);
    k_bcount<<<256, 256, 0, stream>>>(dst, bucketCount, E, npp);
    k_bscan<<<1, 64, 0, stream>>>(bucketCount, bbase, bucketCursor);
    k_bucket<<<nA3, 256, 0, stream>>>(src, dst, bucketCursor, pairs, E, npp);
    k_count_part<<<NPART * KB, 256, 0, stream>>>(pairs, bbase, bucketCount, cntarr, npp);
    k_indeg<<<(N + 255) / 256, 256, 0, stream>>>(cntarr, indeg, N, npp);
    k_scan_local<<<nscan, 256, 0, stream>>>(indeg, row_ptr, partials, N);
    k_scan_partials<<<1, 256, 0, stream>>>(partials, nscan);
    k_finalize<<<(N + 255) / 256, 256, 0, stream>>>(row_ptr, partials, indeg, dinv, N, E);
    k_bases<<<(N + 255) / 256, 256, 0, stream>>>(cntarr, row_ptr, N, npp);
    k_fill2<<<NPART * KB, 256, 0, stream>>>(pairs, bbase, bucketCount, cntarr,
                                            colarr, npp);

    k_gemm128_mfma<<<ngemm, 256, 0, stream>>>(x, Bp1, dinv, (unsigned char*)h1f8, N);
    k_agg_relu<<<(N + 3) / 4, 256, 0, stream>>>(h1f8, dinv, row_ptr, colarr, b1, a1b, N);
    k_gemm64_mfma<<<ngemm, 256, 0, stream>>>(a1b, Bp2, dinv, (unsigned short*)h2b, N);
    k_agg_lsm<<<(N + 3) / 4, 256, 0, stream>>>(h2b, dinv, row_ptr, colarr, b2, out, N);
}